// Round 6
// baseline (1004.393 us; speedup 1.0000x reference)
//
#include <hip/hip_runtime.h>
#include <hip/hip_bf16.h>

typedef __attribute__((ext_vector_type(8))) short s8_t;    // 8 x bf16 (4 VGPR)
typedef __attribute__((ext_vector_type(4))) float f4_t;    // MFMA accumulator

// ---------- helpers ----------
__device__ __forceinline__ unsigned short f2bf(float f) {
  union { float f; unsigned u; } x; x.f = f;
  unsigned r = x.u + 0x7fffu + ((x.u >> 16) & 1u);  // RNE (bf16-tolerant paths only)
  return (unsigned short)(r >> 16);
}

// truncation split, elementwise: hi = top16(v), lo = top16(v - hi).
// Bit-identical to round-3 split2 per element.
__device__ __forceinline__ void split1(float v, unsigned short& h, unsigned short& l) {
  unsigned b = __float_as_uint(v);
  unsigned hb = b & 0xFFFF0000u;
  h = (unsigned short)(b >> 16);
  float lo = v - __uint_as_float(hb);
  l = (unsigned short)(__float_as_uint(lo) >> 16);
}

// pair split with round-3 packing (for the Wq/Wk in-kernel staging path)
__device__ __forceinline__ void split2(float e0, float e1, unsigned& hp, unsigned& lp) {
  unsigned b0 = __float_as_uint(e0), b1 = __float_as_uint(e1);
  unsigned h0 = b0 & 0xFFFF0000u, h1 = b1 & 0xFFFF0000u;
  hp = (b0 >> 16) | h1;
  float l0 = e0 - __uint_as_float(h0), l1 = e1 - __uint_as_float(h1);
  lp = (__float_as_uint(l0) >> 16) | (__float_as_uint(l1) & 0xFFFF0000u);
}

__device__ __forceinline__ void gload16(const void* g, void* l) {
  __builtin_amdgcn_global_load_lds(
      (const __attribute__((address_space(1))) void*)g,
      (__attribute__((address_space(3))) void*)l, 16, 0, 0);
}

// T1 XCD swizzle: contiguous chunk of the flat grid per XCD (nwg % 8 == 0 for all grids here)
__device__ __forceinline__ void swz_grid(int& bx, int& by, int& bz) {
  const int gx = gridDim.x, gy = gridDim.y;
  const int nwg = gx * gy * gridDim.z;
  const int flat = (blockIdx.z * gy + blockIdx.y) * gx + blockIdx.x;
  const int s = (flat & 7) * (nwg >> 3) + (flat >> 3);
  bx = s % gx;
  const int r = s / gx;
  by = r % gy;
  bz = r / gy;
}

// ---------- fp32 -> bf16 convert (Wv) ----------
__global__ __launch_bounds__(256) void k_convert(const float* __restrict__ in,
                                                 unsigned short* __restrict__ out, int n) {
  int i = (blockIdx.x * 256 + threadIdx.x) * 8;
  if (i >= n) return;
  float4 a = *(const float4*)(in + i);
  float4 b = *(const float4*)(in + i + 4);
  ushort4 u0; u0.x = f2bf(a.x); u0.y = f2bf(a.y); u0.z = f2bf(a.z); u0.w = f2bf(a.w);
  ushort4 u1; u1.x = f2bf(b.x); u1.y = f2bf(b.y); u1.z = f2bf(b.z); u1.w = f2bf(b.w);
  *(ushort4*)(out + i) = u0;
  *(ushort4*)(out + i + 4) = u1;
}

// ---------- fused transpose+split: fp32 [1024][1024]/batch ->
//   natural hi/lo bf16 planes + transposed hi/lo bf16 planes ----------
__global__ __launch_bounds__(256) void k_tsplit(const float* __restrict__ in,
                                                unsigned short* __restrict__ nh,
                                                unsigned short* __restrict__ nl,
                                                unsigned short* __restrict__ th,
                                                unsigned short* __restrict__ tl) {
  __shared__ float tile[64][65];
  const int t = threadIdx.x, bz = blockIdx.z;
  const int r0 = blockIdx.y * 64, c0 = blockIdx.x * 64;
  const float* ip = in + (size_t)bz * 1048576;
  const size_t ob = (size_t)bz * 1048576;
  const int tr = t >> 4, tc = (t & 15) * 4;
#pragma unroll
  for (int p = 0; p < 4; ++p) {
    int r = p * 16 + tr;
    float4 v = *(const float4*)(ip + (size_t)(r0 + r) * 1024 + c0 + tc);
    ushort4 h, l;
    split1(v.x, h.x, l.x); split1(v.y, h.y, l.y);
    split1(v.z, h.z, l.z); split1(v.w, h.w, l.w);
    *(ushort4*)(nh + ob + (size_t)(r0 + r) * 1024 + c0 + tc) = h;
    *(ushort4*)(nl + ob + (size_t)(r0 + r) * 1024 + c0 + tc) = l;
    tile[r][tc] = v.x; tile[r][tc + 1] = v.y; tile[r][tc + 2] = v.z; tile[r][tc + 3] = v.w;
  }
  __syncthreads();
#pragma unroll
  for (int p = 0; p < 4; ++p) {
    int n = p * 16 + tr;
    float a = tile[tc][n], b = tile[tc + 1][n], c = tile[tc + 2][n], d = tile[tc + 3][n];
    ushort4 h, l;
    split1(a, h.x, l.x); split1(b, h.y, l.y); split1(c, h.z, l.z); split1(d, h.w, l.w);
    *(ushort4*)(th + ob + (size_t)(c0 + n) * 1024 + r0 + tc) = h;
    *(ushort4*)(tl + ob + (size_t)(c0 + n) * 1024 + r0 + tc) = l;
  }
}

// ---------- fp32 [1024][1024]/batch -> bf16 transposed (for z) ----------
__global__ __launch_bounds__(256) void k_transpbf(const float* __restrict__ in,
                                                  unsigned short* __restrict__ outt) {
  __shared__ unsigned short tile[64][72];
  const int t = threadIdx.x, b = blockIdx.z;
  const int r0 = blockIdx.y * 64, c0 = blockIdx.x * 64;
  const float* ip = in + (size_t)b * 1048576;
  const int tr = t >> 4, tc = (t & 15) * 4;
#pragma unroll
  for (int p = 0; p < 4; ++p) {
    int r = p * 16 + tr;
    float4 v = *(const float4*)(ip + (size_t)(r0 + r) * 1024 + c0 + tc);
    tile[r][tc] = f2bf(v.x); tile[r][tc + 1] = f2bf(v.y);
    tile[r][tc + 2] = f2bf(v.z); tile[r][tc + 3] = f2bf(v.w);
  }
  __syncthreads();
#pragma unroll
  for (int p = 0; p < 4; ++p) {
    int n = p * 16 + tr;
    ushort4 w;
    w.x = tile[tc][n]; w.y = tile[tc + 1][n]; w.z = tile[tc + 2][n]; w.w = tile[tc + 3][n];
    *(ushort4*)(outt + (size_t)b * 1048576 + (size_t)(c0 + n) * 1024 + r0 + tc) = w;
  }
}

// ---------- 3-term plane GEMM (gload_lds, m97 structure): es and ec ----------
// C[m][n] = sum_k (Ah+Al)[m][k]*(Bh+Bl)[n][k] via Ah*Bh + Ah*Bl + Al*Bh.
// All four operands bf16 planes, K-contiguous. 128x128 tile, BK=32, 4 waves.
__global__ __launch_bounds__(256) void k_es3p(
    const unsigned short* __restrict__ Ah, const unsigned short* __restrict__ Al,
    long long sA, int lda,
    const unsigned short* __restrict__ Bh, const unsigned short* __restrict__ Bl,
    long long sB, int ldb,
    float* __restrict__ C, int ldc, long long sC, int K) {
  __shared__ __align__(16) unsigned short smAh[4096], smAl[4096], smBh[4096], smBl[4096];
  int bx, by, bz; swz_grid(bx, by, bz);
  const int tid = threadIdx.x, lane = tid & 63, wave = tid >> 6;
  const int wr = wave >> 1, wc = wave & 1;
  const int m0 = bx * 128, n0 = by * 128;

  const int ch0 = wave * 64 + lane, ch1 = ch0 + 256;
  const int r0 = ch0 >> 2, kc0 = (ch0 & 3) * 8, r1 = ch1 >> 2, kc1 = (ch1 & 3) * 8;
  const unsigned short* pah0 = Ah + (long long)bz * sA + (long long)(m0 + r0) * lda + kc0;
  const unsigned short* pah1 = Ah + (long long)bz * sA + (long long)(m0 + r1) * lda + kc1;
  const unsigned short* pal0 = Al + (long long)bz * sA + (long long)(m0 + r0) * lda + kc0;
  const unsigned short* pal1 = Al + (long long)bz * sA + (long long)(m0 + r1) * lda + kc1;
  const unsigned short* pbh0 = Bh + (long long)bz * sB + (long long)(n0 + r0) * ldb + kc0;
  const unsigned short* pbh1 = Bh + (long long)bz * sB + (long long)(n0 + r1) * ldb + kc1;
  const unsigned short* pbl0 = Bl + (long long)bz * sB + (long long)(n0 + r0) * ldb + kc0;
  const unsigned short* pbl1 = Bl + (long long)bz * sB + (long long)(n0 + r1) * ldb + kc1;
  char* dAh0 = (char*)smAh + wave * 1024; char* dAh1 = dAh0 + 4096;
  char* dAl0 = (char*)smAl + wave * 1024; char* dAl1 = dAl0 + 4096;
  char* dBh0 = (char*)smBh + wave * 1024; char* dBh1 = dBh0 + 4096;
  char* dBl0 = (char*)smBl + wave * 1024; char* dBl1 = dBl0 + 4096;

  const int lr = lane & 15, lg = lane >> 4;
  const int fa = (wr * 64 + lr) * 32 + lg * 8;
  const int fb = (wc * 64 + lr) * 32 + lg * 8;

  f4_t acc[4][4];
#pragma unroll
  for (int i = 0; i < 4; ++i)
#pragma unroll
    for (int j = 0; j < 4; ++j) acc[i][j] = (f4_t)0.f;

  for (int k0 = 0; k0 < K; k0 += 32) {
    gload16(pah0, dAh0); gload16(pah1, dAh1);
    gload16(pal0, dAl0); gload16(pal1, dAl1);
    gload16(pbh0, dBh0); gload16(pbh1, dBh1);
    gload16(pbl0, dBl0); gload16(pbl1, dBl1);
    pah0 += 32; pah1 += 32; pal0 += 32; pal1 += 32;
    pbh0 += 32; pbh1 += 32; pbl0 += 32; pbl1 += 32;
    __syncthreads();
    s8_t fah[4], fbh[4], ft[4];
#pragma unroll
    for (int f = 0; f < 4; ++f) {
      fah[f] = *(const s8_t*)(smAh + fa + f * 512);
      fbh[f] = *(const s8_t*)(smBh + fb + f * 512);
    }
#pragma unroll
    for (int i = 0; i < 4; ++i)
#pragma unroll
      for (int j = 0; j < 4; ++j)
        acc[i][j] = __builtin_amdgcn_mfma_f32_16x16x32_bf16(fah[i], fbh[j], acc[i][j], 0, 0, 0);
#pragma unroll
    for (int f = 0; f < 4; ++f) ft[f] = *(const s8_t*)(smBl + fb + f * 512);
#pragma unroll
    for (int i = 0; i < 4; ++i)
#pragma unroll
      for (int j = 0; j < 4; ++j)
        acc[i][j] = __builtin_amdgcn_mfma_f32_16x16x32_bf16(fah[i], ft[j], acc[i][j], 0, 0, 0);
#pragma unroll
    for (int f = 0; f < 4; ++f) ft[f] = *(const s8_t*)(smAl + fa + f * 512);
#pragma unroll
    for (int i = 0; i < 4; ++i)
#pragma unroll
      for (int j = 0; j < 4; ++j)
        acc[i][j] = __builtin_amdgcn_mfma_f32_16x16x32_bf16(ft[i], fbh[j], acc[i][j], 0, 0, 0);
    __syncthreads();
  }

#pragma unroll
  for (int i = 0; i < 4; ++i) {
    const int rbase = m0 + wr * 64 + i * 16 + lg * 4;
#pragma unroll
    for (int j = 0; j < 4; ++j) {
      const int col = n0 + wc * 64 + j * 16 + lr;
#pragma unroll
      for (int e = 0; e < 4; ++e)
        C[(long long)bz * sC + (long long)(rbase + e) * ldc + col] = acc[i][j][e];
    }
  }
}

// ---------- merged q/k projection: A = transposed input planes (gload_lds),
// B = Wq/Wk fp32 (reg-staged split), out = split bf16 planes [n][128] ----------
// grid (8, 2, nb): by=0 -> q path, by=1 -> k path. K = 1024.
__global__ __launch_bounds__(256) void k_qk3p(
    const unsigned short* __restrict__ Axh, const unsigned short* __restrict__ Axl,
    const unsigned short* __restrict__ Ayh, const unsigned short* __restrict__ Ayl,
    const float* __restrict__ Wqf, const float* __restrict__ Wkf,
    const float* __restrict__ bqf, const float* __restrict__ bkf,
    unsigned short* __restrict__ Qh, unsigned short* __restrict__ Ql,
    unsigned short* __restrict__ Kh, unsigned short* __restrict__ Kl) {
  __shared__ __align__(16) unsigned short smAh[4096], smAl[4096], smBh[4096], smBl[4096];
  int bx, by, bz; swz_grid(bx, by, bz);
  const unsigned short* Ah = by ? Ayh : Axh;
  const unsigned short* Al = by ? Ayl : Axl;
  const float* Bf = by ? Wkf : Wqf;
  const float* bias = by ? bkf : bqf;
  unsigned short* Oh = by ? Kh : Qh;
  unsigned short* Ol = by ? Kl : Ql;

  const int tid = threadIdx.x, lane = tid & 63, wave = tid >> 6;
  const int wr = wave >> 1, wc = wave & 1;
  const int m0 = bx * 128;  // n-rows; o-cols tile is the full 128

  const int ch0 = wave * 64 + lane, ch1 = ch0 + 256;
  const int r0 = ch0 >> 2, kc0 = (ch0 & 3) * 8, r1 = ch1 >> 2, kc1 = (ch1 & 3) * 8;
  const unsigned short* pah0 = Ah + (long long)bz * 1048576 + (long long)(m0 + r0) * 1024 + kc0;
  const unsigned short* pah1 = Ah + (long long)bz * 1048576 + (long long)(m0 + r1) * 1024 + kc1;
  const unsigned short* pal0 = Al + (long long)bz * 1048576 + (long long)(m0 + r0) * 1024 + kc0;
  const unsigned short* pal1 = Al + (long long)bz * 1048576 + (long long)(m0 + r1) * 1024 + kc1;
  char* dAh0 = (char*)smAh + wave * 1024; char* dAh1 = dAh0 + 4096;
  char* dAl0 = (char*)smAl + wave * 1024; char* dAl1 = dAl0 + 4096;

  // B staging (reg-split, round-3 pattern): thread t covers o-row t>>1, k-cols [(t&1)*16,+16)
  const int sr = tid >> 1, sh = (tid & 1) * 16;
  const float* bg = Bf + (long long)sr * 1024 + sh;
  const int wbase = sr * 32 + sh;

  const int lr = lane & 15, lg = lane >> 4;
  const int fa = (wr * 64 + lr) * 32 + lg * 8;
  const int fb = (wc * 64 + lr) * 32 + lg * 8;

  f4_t acc[4][4];
#pragma unroll
  for (int i = 0; i < 4; ++i)
#pragma unroll
    for (int j = 0; j < 4; ++j) acc[i][j] = (f4_t)0.f;

  for (int k0 = 0; k0 < 1024; k0 += 32) {
    gload16(pah0, dAh0); gload16(pah1, dAh1);
    gload16(pal0, dAl0); gload16(pal1, dAl1);
    pah0 += 32; pah1 += 32; pal0 += 32; pal1 += 32;
    float bv[16];
#pragma unroll
    for (int p = 0; p < 4; ++p) *(float4*)(bv + p * 4) = *(const float4*)(bg + p * 4);
    bg += 32;
    unsigned bh[8], bl[8];
#pragma unroll
    for (int p = 0; p < 8; ++p) split2(bv[2 * p], bv[2 * p + 1], bh[p], bl[p]);
    *(uint4*)(smBh + wbase) = *(uint4*)(bh);
    *(uint4*)(smBh + wbase + 8) = *(uint4*)(bh + 4);
    *(uint4*)(smBl + wbase) = *(uint4*)(bl);
    *(uint4*)(smBl + wbase + 8) = *(uint4*)(bl + 4);
    __syncthreads();
    s8_t fah[4], fbh[4], ft[4];
#pragma unroll
    for (int f = 0; f < 4; ++f) {
      fah[f] = *(const s8_t*)(smAh + fa + f * 512);
      fbh[f] = *(const s8_t*)(smBh + fb + f * 512);
    }
#pragma unroll
    for (int i = 0; i < 4; ++i)
#pragma unroll
      for (int j = 0; j < 4; ++j)
        acc[i][j] = __builtin_amdgcn_mfma_f32_16x16x32_bf16(fah[i], fbh[j], acc[i][j], 0, 0, 0);
#pragma unroll
    for (int f = 0; f < 4; ++f) ft[f] = *(const s8_t*)(smBl + fb + f * 512);
#pragma unroll
    for (int i = 0; i < 4; ++i)
#pragma unroll
      for (int j = 0; j < 4; ++j)
        acc[i][j] = __builtin_amdgcn_mfma_f32_16x16x32_bf16(fah[i], ft[j], acc[i][j], 0, 0, 0);
#pragma unroll
    for (int f = 0; f < 4; ++f) ft[f] = *(const s8_t*)(smAl + fa + f * 512);
#pragma unroll
    for (int i = 0; i < 4; ++i)
#pragma unroll
      for (int j = 0; j < 4; ++j)
        acc[i][j] = __builtin_amdgcn_mfma_f32_16x16x32_bf16(ft[i], fbh[j], acc[i][j], 0, 0, 0);
    __syncthreads();
  }

  // epilogue: fp32 acc + bias[col] -> split bf16 hi/lo planes [n][128]
#pragma unroll
  for (int i = 0; i < 4; ++i) {
    const int rbase = m0 + wr * 64 + i * 16 + lg * 4;
#pragma unroll
    for (int j = 0; j < 4; ++j) {
      const int col = wc * 64 + j * 16 + lr;
      const float bc = bias[col];
#pragma unroll
      for (int e = 0; e < 4; ++e) {
        float v = acc[i][j][e] + bc;
        unsigned short h, l;
        split1(v, h, l);
        const long long off = (long long)bz * 131072 + (long long)(rbase + e) * 128 + col;
        Oh[off] = h;
        Ol[off] = l;
      }
    }
  }
}

// ---------- bf16 NT MFMA GEMM (gload_lds) for v and out, + XCD swizzle ----------
template <int BIAS_MODE, bool OUT_BF16, bool RESID>
__global__ __launch_bounds__(256) void k_mfma(
    const unsigned short* __restrict__ A, int lda, long long sA,
    const unsigned short* __restrict__ B, int ldb, long long sB,
    void* __restrict__ Cp, int ldc, long long sC,
    const float* __restrict__ bias,
    const float* __restrict__ resid, long long sR, int K) {
  __shared__ __align__(16) unsigned short As[4096];
  __shared__ __align__(16) unsigned short Bs[4096];
  int bxs, bys, bz; swz_grid(bxs, bys, bz);
  const int tid = threadIdx.x;
  const int lane = tid & 63, wave = tid >> 6;
  const int wr = wave >> 1, wc = wave & 1;
  const int m0 = bxs * 128, n0 = bys * 128;

  const int ch0 = wave * 64 + lane, ch1 = ch0 + 256;
  const unsigned short* pa0 = A + (long long)bz * sA + (long long)(m0 + (ch0 >> 2)) * lda + (ch0 & 3) * 8;
  const unsigned short* pa1 = A + (long long)bz * sA + (long long)(m0 + (ch1 >> 2)) * lda + (ch1 & 3) * 8;
  const unsigned short* pb0 = B + (long long)bz * sB + (long long)(n0 + (ch0 >> 2)) * ldb + (ch0 & 3) * 8;
  const unsigned short* pb1 = B + (long long)bz * sB + (long long)(n0 + (ch1 >> 2)) * ldb + (ch1 & 3) * 8;
  char* la0 = (char*)As + wave * 1024;
  char* la1 = la0 + 4096;
  char* lb0 = (char*)Bs + wave * 1024;
  char* lb1 = lb0 + 4096;

  const int lr = lane & 15, lg = lane >> 4;
  const unsigned short* arp = As + (wr * 64 + lr) * 32 + lg * 8;
  const unsigned short* brp = Bs + (wc * 64 + lr) * 32 + lg * 8;

  f4_t acc[4][4];
#pragma unroll
  for (int i = 0; i < 4; ++i)
#pragma unroll
    for (int j = 0; j < 4; ++j) acc[i][j] = (f4_t)0.f;

  for (int k0 = 0; k0 < K; k0 += 32) {
    gload16(pa0, la0); gload16(pa1, la1);
    gload16(pb0, lb0); gload16(pb1, lb1);
    pa0 += 32; pa1 += 32; pb0 += 32; pb1 += 32;
    __syncthreads();
    s8_t af[4], bf[4];
#pragma unroll
    for (int f = 0; f < 4; ++f) {
      af[f] = *(const s8_t*)(arp + f * 16 * 32);
      bf[f] = *(const s8_t*)(brp + f * 16 * 32);
    }
#pragma unroll
    for (int i = 0; i < 4; ++i)
#pragma unroll
      for (int j = 0; j < 4; ++j)
        acc[i][j] = __builtin_amdgcn_mfma_f32_16x16x32_bf16(af[i], bf[j], acc[i][j], 0, 0, 0);
    __syncthreads();
  }

#pragma unroll
  for (int i = 0; i < 4; ++i) {
    const int rbase = m0 + wr * 64 + i * 16 + lg * 4;
#pragma unroll
    for (int j = 0; j < 4; ++j) {
      const int col = n0 + wc * 64 + j * 16 + lr;
#pragma unroll
      for (int e = 0; e < 4; ++e) {
        const int row = rbase + e;
        float v = acc[i][j][e];
        if (BIAS_MODE == 1) v += bias[row];
        const long long off = (long long)bz * sC + (long long)row * ldc + col;
        if (RESID) v += resid[(long long)bz * sR + (long long)row * ldc + col];
        if (OUT_BF16) ((unsigned short*)Cp)[off] = f2bf(v);
        else          ((float*)Cp)[off] = v;
      }
    }
  }
}

// ---------- fused triple softmax ----------
__device__ __forceinline__ float wave_red_max(float v) {
#pragma unroll
  for (int o = 32; o > 0; o >>= 1) v = fmaxf(v, __shfl_down(v, o, 64));
  return v;
}
__device__ __forceinline__ float wave_red_sum(float v) {
#pragma unroll
  for (int o = 32; o > 0; o >>= 1) v += __shfl_down(v, o, 64);
  return v;
}
__device__ __forceinline__ float block_red_max(float v, float* red) {
  v = wave_red_max(v);
  if ((threadIdx.x & 63) == 0) red[threadIdx.x >> 6] = v;
  __syncthreads();
  v = fmaxf(fmaxf(red[0], red[1]), fmaxf(red[2], red[3]));
  __syncthreads();
  return v;
}
__device__ __forceinline__ float block_red_sum(float v, float* red) {
  v = wave_red_sum(v);
  if ((threadIdx.x & 63) == 0) red[threadIdx.x >> 6] = v;
  __syncthreads();
  v = red[0] + red[1] + red[2] + red[3];
  __syncthreads();
  return v;
}

__global__ __launch_bounds__(256) void k_combine(float* __restrict__ ec,
                                                 const float* __restrict__ es) {
  __shared__ float red[4];
  const size_t row = blockIdx.x;
  float* cp = ec + row * 1024;
  const float* sp = es + row * 1024;
  const int tid = threadIdx.x;
  float4 c4 = ((const float4*)cp)[tid];
  float4 s4 = ((const float4*)sp)[tid];

  float mx = fmaxf(fmaxf(c4.x, c4.y), fmaxf(c4.z, c4.w));
  mx = block_red_max(mx, red);
  float e0 = __expf(c4.x - mx), e1 = __expf(c4.y - mx);
  float e2 = __expf(c4.z - mx), e3 = __expf(c4.w - mx);
  float sc = block_red_sum(e0 + e1 + e2 + e3, red);

  float t0 = -s4.x, t1 = -s4.y, t2 = -s4.z, t3 = -s4.w;
  float mt = fmaxf(fmaxf(t0, t1), fmaxf(t2, t3));
  mt = block_red_max(mt, red);
  float f0 = __expf(t0 - mt), f1 = __expf(t1 - mt);
  float f2 = __expf(t2 - mt), f3 = __expf(t3 - mt);
  float ss = block_red_sum(f0 + f1 + f2 + f3, red);

  const float rc = 1.f / sc, rs = 1.f / ss;
  float g0 = __expf((e0 * rc) * (f0 * rs));
  float g1 = __expf((e1 * rc) * (f1 * rs));
  float g2 = __expf((e2 * rc) * (f2 * rs));
  float g3 = __expf((e3 * rc) * (f3 * rs));
  float s3 = block_red_sum(g0 + g1 + g2 + g3, red);
  const float r3 = 1.f / s3;
  ushort4 o;
  o.x = f2bf(g0 * r3); o.y = f2bf(g1 * r3); o.z = f2bf(g2 * r3); o.w = f2bf(g3 * r3);
  ((ushort4*)cp)[tid] = o;
}

// ---------- launch ----------
extern "C" void kernel_launch(void* const* d_in, const int* in_sizes, int n_in,
                              void* d_out, int out_size, void* d_ws, size_t ws_size,
                              hipStream_t stream) {
  const float* z = (const float*)d_in[0];
  const float* x = (const float*)d_in[1];
  const float* y = (const float*)d_in[2];
  const float* Wq = (const float*)d_in[3];
  const float* bq = (const float*)d_in[4];
  const float* Wk = (const float*)d_in[5];
  const float* bk = (const float*)d_in[6];
  const float* Wv = (const float*)d_in[7];
  const float* bv = (const float*)d_in[8];
  float* out = (float*)d_out;

  // ws (288 MiB):
  // R_es [0,128M):   es fp32 -> (post-combine) z_t bf16 [0,64M) | v_bf [64M,128M)
  // R_ec [128,256M): per-chunk planes (8 batches x {xh,xl,yh,yl,xth,xtl,yth,ytl} = 128M)
  //                  -> ec fp32 (attn bf16 in-place, row stride 2048)
  // R3  [256,288M):  qh,ql,kh,kl split planes (8M each) -> wv bf16 (after ec)
  char* ws = (char*)d_ws;
  float* es = (float*)ws;
  unsigned short* z_t = (unsigned short*)ws;
  unsigned short* v_bf = z_t + 33554432;
  char* wsB = ws + 134217728;
  unsigned short* xh  = (unsigned short*)wsB;
  unsigned short* xl  = xh + 8388608;
  unsigned short* yh  = xl + 8388608;
  unsigned short* yl  = yh + 8388608;
  unsigned short* xth = yl + 8388608;
  unsigned short* xtl = xth + 8388608;
  unsigned short* yth = xtl + 8388608;
  unsigned short* ytl = yth + 8388608;
  float* ec = (float*)wsB;
  unsigned short* attn = (unsigned short*)wsB;
  char* wsC = ws + 268435456;
  unsigned short* qh = (unsigned short*)wsC;
  unsigned short* ql = qh + 4194304;
  unsigned short* kh = ql + 4194304;
  unsigned short* kl = kh + 4194304;
  unsigned short* wv = (unsigned short*)wsC;

  dim3 blk(256);
  for (int c = 0; c < 4; ++c) {
    const size_t boff = (size_t)c * 8 * 1048576;
    // transpose+split x,y chunk -> natural + transposed hi/lo planes
    hipLaunchKernelGGL(k_tsplit, dim3(16, 16, 8), blk, 0, stream, x + boff, xh, xl, xth, xtl);
    hipLaunchKernelGGL(k_tsplit, dim3(16, 16, 8), blk, 0, stream, y + boff, yh, yl, yth, ytl);
    // es[b][m][d] = x[m][:].y[d][:] (3-term planes)
    hipLaunchKernelGGL(k_es3p, dim3(8, 8, 8), blk, 0, stream,
                       xh, xl, 1048576LL, 1024, yh, yl, 1048576LL, 1024,
                       es + boff, 1024, 1048576LL, 1024);
    // q_t,k_t[n][o] -> split bf16 planes (merged launch)
    hipLaunchKernelGGL(k_qk3p, dim3(8, 2, 8), blk, 0, stream,
                       xth, xtl, yth, ytl, Wq, Wk, bq, bk,
                       qh + c * 8 * 131072, ql + c * 8 * 131072,
                       kh + c * 8 * 131072, kl + c * 8 * 131072);
  }
  // ec[b][i][j] = q_t[i][:].k_t[j][:] (K=128, 3-term planes)
  hipLaunchKernelGGL(k_es3p, dim3(8, 8, 32), blk, 0, stream,
                     qh, ql, 131072LL, 128, kh, kl, 131072LL, 128,
                     ec, 1024, 1048576LL, 128);
  // triple softmax -> attn bf16 in-place in ec rows
  hipLaunchKernelGGL(k_combine, dim3(32768), blk, 0, stream, ec, es);
  // z^T bf16 (es dead) ; Wv bf16 (q/k planes dead)
  hipLaunchKernelGGL(k_transpbf, dim3(16, 16, 32), blk, 0, stream, z, z_t);
  hipLaunchKernelGGL(k_convert, dim3(512), blk, 0, stream, Wv, wv, 1048576);
  // v[b][o][n] = Wv[o][:] . z_t[n][:] + bv[o] -> bf16
  hipLaunchKernelGGL((k_mfma<1, true, false>), dim3(8, 8, 32), blk, 0, stream,
                     wv, 1024, 0LL, z_t, 1024, 1048576LL, (void*)v_bf, 1024, 1048576LL,
                     bv, (const float*)nullptr, 0LL, 1024);
  // out[b][c][m] = z[b][c][m] + v[c][:] . attn[m][:]
  hipLaunchKernelGGL((k_mfma<0, false, true>), dim3(8, 8, 32), blk, 0, stream,
                     v_bf, 1024, 1048576LL, attn, 2048, 2097152LL, (void*)out, 1024, 1048576LL,
                     (const float*)nullptr, z, 1048576LL, 1024);
}

// Round 7
// 877.324 us; speedup vs baseline: 1.1448x; 1.1448x over previous
//
#include <hip/hip_runtime.h>
#include <hip/hip_bf16.h>

typedef __attribute__((ext_vector_type(8))) short s8_t;    // 8 x bf16 (4 VGPR)
typedef __attribute__((ext_vector_type(4))) float f4_t;    // MFMA accumulator

// ---------- helpers ----------
__device__ __forceinline__ unsigned short f2bf(float f) {
  union { float f; unsigned u; } x; x.f = f;
  unsigned r = x.u + 0x7fffu + ((x.u >> 16) & 1u);  // RNE
  return (unsigned short)(r >> 16);
}

// split fp32 pair -> packed bf16 hi pair + packed bf16 lo pair (truncation split:
// hi = top16(x), lo = top16(x - hi); dropped residual <= 2^-16 |x|)
__device__ __forceinline__ void split2(float e0, float e1, unsigned& hp, unsigned& lp) {
  unsigned b0 = __float_as_uint(e0), b1 = __float_as_uint(e1);
  unsigned h0 = b0 & 0xFFFF0000u, h1 = b1 & 0xFFFF0000u;
  hp = (b0 >> 16) | h1;
  float l0 = e0 - __uint_as_float(h0), l1 = e1 - __uint_as_float(h1);
  lp = (__float_as_uint(l0) >> 16) | (__float_as_uint(l1) & 0xFFFF0000u);
}

__device__ __forceinline__ void gload16(const void* g, void* l) {
  __builtin_amdgcn_global_load_lds(
      (const __attribute__((address_space(1))) void*)g,
      (__attribute__((address_space(3))) void*)l, 16, 0, 0);
}

// T1 XCD swizzle (nwg % 8 == 0 for all grids using this)
__device__ __forceinline__ void swz_grid(int& bx, int& by, int& bz) {
  const int gx = gridDim.x, gy = gridDim.y;
  const int nwg = gx * gy * gridDim.z;
  const int flat = (blockIdx.z * gy + blockIdx.y) * gx + blockIdx.x;
  const int s = (flat & 7) * (nwg >> 3) + (flat >> 3);
  bx = s % gx;
  const int r = s / gx;
  by = r % gy;
  bz = r / gy;
}

// ---------- fp32 -> bf16 elementwise convert (for Wv) ----------
__global__ __launch_bounds__(256) void k_convert(const float* __restrict__ in,
                                                 unsigned short* __restrict__ out, int n) {
  int i = (blockIdx.x * 256 + threadIdx.x) * 8;
  if (i >= n) return;
  float4 a = *(const float4*)(in + i);
  float4 b = *(const float4*)(in + i + 4);
  ushort4 u0; u0.x = f2bf(a.x); u0.y = f2bf(a.y); u0.z = f2bf(a.z); u0.w = f2bf(a.w);
  ushort4 u1; u1.x = f2bf(b.x); u1.y = f2bf(b.y); u1.z = f2bf(b.z); u1.w = f2bf(b.w);
  *(ushort4*)(out + i) = u0;
  *(ushort4*)(out + i + 4) = u1;
}

// ---------- fp32 [1024][1024]/batch -> fp32 transposed ----------
__global__ __launch_bounds__(256) void k_transp32(const float* __restrict__ in,
                                                  float* __restrict__ out) {
  __shared__ float tile[64][65];
  const int t = threadIdx.x, b = blockIdx.z;
  const int r0 = blockIdx.y * 64, c0 = blockIdx.x * 64;
  const float* ip = in + (size_t)b * 1048576;
  float* op = out + (size_t)b * 1048576;
  const int tr = t >> 4, tc = (t & 15) * 4;
#pragma unroll
  for (int p = 0; p < 4; ++p) {
    int r = p * 16 + tr;
    float4 v = *(const float4*)(ip + (size_t)(r0 + r) * 1024 + c0 + tc);
    tile[r][tc] = v.x; tile[r][tc + 1] = v.y; tile[r][tc + 2] = v.z; tile[r][tc + 3] = v.w;
  }
  __syncthreads();
#pragma unroll
  for (int p = 0; p < 4; ++p) {
    int n = p * 16 + tr;
    float4 w;
    w.x = tile[tc][n]; w.y = tile[tc + 1][n]; w.z = tile[tc + 2][n]; w.w = tile[tc + 3][n];
    *(float4*)(op + (size_t)(c0 + n) * 1024 + r0 + tc) = w;
  }
}

// ---------- fp32 [1024][1024]/batch -> bf16 transposed (for z) ----------
__global__ __launch_bounds__(256) void k_transpbf(const float* __restrict__ in,
                                                  unsigned short* __restrict__ outt) {
  __shared__ unsigned short tile[64][72];
  const int t = threadIdx.x, b = blockIdx.z;
  const int r0 = blockIdx.y * 64, c0 = blockIdx.x * 64;
  const float* ip = in + (size_t)b * 1048576;
  const int tr = t >> 4, tc = (t & 15) * 4;
#pragma unroll
  for (int p = 0; p < 4; ++p) {
    int r = p * 16 + tr;
    float4 v = *(const float4*)(ip + (size_t)(r0 + r) * 1024 + c0 + tc);
    tile[r][tc] = f2bf(v.x); tile[r][tc + 1] = f2bf(v.y);
    tile[r][tc + 2] = f2bf(v.z); tile[r][tc + 3] = f2bf(v.w);
  }
  __syncthreads();
#pragma unroll
  for (int p = 0; p < 4; ++p) {
    int n = p * 16 + tr;
    ushort4 w;
    w.x = tile[tc][n]; w.y = tile[tc + 1][n]; w.z = tile[tc + 2][n]; w.w = tile[tc + 3][n];
    *(ushort4*)(outt + (size_t)b * 1048576 + (size_t)(c0 + n) * 1024 + r0 + tc) = w;
  }
}

// split + write one 32-fp32 stripe (16 A + 16 B) into the 4 planes of buf
__device__ __forceinline__ void split_write(unsigned short* buf, int wbase,
                                            const float* av, const float* bv) {
  unsigned ah[8], al[8], bh[8], bl[8];
#pragma unroll
  for (int p = 0; p < 8; ++p) {
    split2(av[2 * p], av[2 * p + 1], ah[p], al[p]);
    split2(bv[2 * p], bv[2 * p + 1], bh[p], bl[p]);
  }
  *(uint4*)(buf + wbase) = *(uint4*)(ah);
  *(uint4*)(buf + wbase + 8) = *(uint4*)(ah + 4);
  *(uint4*)(buf + 4096 + wbase) = *(uint4*)(al);
  *(uint4*)(buf + 4096 + wbase + 8) = *(uint4*)(al + 4);
  *(uint4*)(buf + 8192 + wbase) = *(uint4*)(bh);
  *(uint4*)(buf + 8192 + wbase + 8) = *(uint4*)(bh + 4);
  *(uint4*)(buf + 12288 + wbase) = *(uint4*)(bl);
  *(uint4*)(buf + 12288 + wbase + 8) = *(uint4*)(bl + 4);
}

// ---------- split-bf16 3-term MFMA GEMM, fp32 operands (round-3 proven) ----------
// C[m][n] = sum_k A[m][k]*B[n][k]; acc += Ah*Bh + Ah*Bl + Al*Bh. 128x128, BK=32.
// BIAS_MODE: 0 none, 2 bias[col]. Output fp32.
template <int BIAS_MODE>
__global__ __launch_bounds__(256) void k_mfma3(
    const float* __restrict__ A, int lda, long long sA,
    const float* __restrict__ B, int ldb, long long sB,
    float* __restrict__ C, int ldc, long long sC,
    const float* __restrict__ bias, int K) {
  __shared__ __align__(16) unsigned short sm[16384];  // Ah Al Bh Bl planes
  const int tid = threadIdx.x;
  const int lane = tid & 63, wave = tid >> 6;
  const int wr = wave >> 1, wc = wave & 1;
  const int bz = blockIdx.z;
  const int m0 = blockIdx.x * 128, n0 = blockIdx.y * 128;

  const int sr = tid >> 1, sh = (tid & 1) * 16;
  const float* ag = A + (long long)bz * sA + (long long)(m0 + sr) * lda + sh;
  const float* bg = B + (long long)bz * sB + (long long)(n0 + sr) * ldb + sh;
  const int wbase = sr * 32 + sh;

  const int lr = lane & 15, lg = lane >> 4;
  const int fa = (wr * 64 + lr) * 32 + lg * 8;
  const int fb = (wc * 64 + lr) * 32 + lg * 8;

  f4_t acc[4][4];
#pragma unroll
  for (int i = 0; i < 4; ++i)
#pragma unroll
    for (int j = 0; j < 4; ++j) acc[i][j] = (f4_t)0.f;

  for (int k0 = 0; k0 < K; k0 += 32) {
    float av[16], bv[16];
#pragma unroll
    for (int p = 0; p < 4; ++p) {
      *(float4*)(av + p * 4) = *(const float4*)(ag + p * 4);
      *(float4*)(bv + p * 4) = *(const float4*)(bg + p * 4);
    }
    split_write(sm, wbase, av, bv);
    ag += 32; bg += 32;
    __syncthreads();
    const unsigned short* Ahp = sm;
    const unsigned short* Alp = sm + 4096;
    const unsigned short* Bhp = sm + 8192;
    const unsigned short* Blp = sm + 12288;
    s8_t fah[4], fbh[4], ftmp[4];
#pragma unroll
    for (int f = 0; f < 4; ++f) {
      fah[f] = *(const s8_t*)(Ahp + fa + f * 512);
      fbh[f] = *(const s8_t*)(Bhp + fb + f * 512);
    }
#pragma unroll
    for (int i = 0; i < 4; ++i)
#pragma unroll
      for (int j = 0; j < 4; ++j)
        acc[i][j] = __builtin_amdgcn_mfma_f32_16x16x32_bf16(fah[i], fbh[j], acc[i][j], 0, 0, 0);
#pragma unroll
    for (int f = 0; f < 4; ++f) ftmp[f] = *(const s8_t*)(Blp + fb + f * 512);
#pragma unroll
    for (int i = 0; i < 4; ++i)
#pragma unroll
      for (int j = 0; j < 4; ++j)
        acc[i][j] = __builtin_amdgcn_mfma_f32_16x16x32_bf16(fah[i], ftmp[j], acc[i][j], 0, 0, 0);
#pragma unroll
    for (int f = 0; f < 4; ++f) ftmp[f] = *(const s8_t*)(Alp + fa + f * 512);
#pragma unroll
    for (int i = 0; i < 4; ++i)
#pragma unroll
      for (int j = 0; j < 4; ++j)
        acc[i][j] = __builtin_amdgcn_mfma_f32_16x16x32_bf16(ftmp[i], fbh[j], acc[i][j], 0, 0, 0);
    __syncthreads();
  }

#pragma unroll
  for (int i = 0; i < 4; ++i) {
    const int rbase = m0 + wr * 64 + i * 16 + lg * 4;
#pragma unroll
    for (int j = 0; j < 4; ++j) {
      const int col = n0 + wc * 64 + j * 16 + lr;
      float bc = (BIAS_MODE == 2) ? bias[col] : 0.f;
#pragma unroll
      for (int e = 0; e < 4; ++e) {
        float v = acc[i][j][e];
        if (BIAS_MODE == 2) v += bc;
        C[(long long)bz * sC + (long long)(rbase + e) * ldc + col] = v;
      }
    }
  }
}

// ---------- bf16 NT MFMA GEMM, 2-PHASE double-buffered (T3 minimum recipe) ----------
// Per tile: STAGE(next, buf^1) early -> ds_read frags(buf) -> 16 MFMA ->
// vmcnt(0) [cheap: loads flew during MFMAs] -> raw s_barrier. One barrier/tile.
// LDS 2 x (8KB A + 8KB B) = 32KB -> 5 blocks/CU ceiling preserved.
template <int BIAS_MODE, bool OUT_BF16, bool RESID>
__global__ __launch_bounds__(256) void k_mfma(
    const unsigned short* __restrict__ A, int lda, long long sA,
    const unsigned short* __restrict__ B, int ldb, long long sB,
    void* __restrict__ Cp, int ldc, long long sC,
    const float* __restrict__ bias,
    const float* __restrict__ resid, long long sR, int K) {
  __shared__ __align__(16) unsigned short As[8192];  // [2 buf][4096]
  __shared__ __align__(16) unsigned short Bs[8192];
  int bxs, bys, bz; swz_grid(bxs, bys, bz);
  const int tid = threadIdx.x;
  const int lane = tid & 63, wave = tid >> 6;
  const int wr = wave >> 1, wc = wave & 1;
  const int m0 = bxs * 128, n0 = bys * 128;

  const int ch0 = wave * 64 + lane, ch1 = ch0 + 256;
  const unsigned short* pa0 = A + (long long)bz * sA + (long long)(m0 + (ch0 >> 2)) * lda + (ch0 & 3) * 8;
  const unsigned short* pa1 = A + (long long)bz * sA + (long long)(m0 + (ch1 >> 2)) * lda + (ch1 & 3) * 8;
  const unsigned short* pb0 = B + (long long)bz * sB + (long long)(n0 + (ch0 >> 2)) * ldb + (ch0 & 3) * 8;
  const unsigned short* pb1 = B + (long long)bz * sB + (long long)(n0 + (ch1 >> 2)) * ldb + (ch1 & 3) * 8;

  const int lr = lane & 15, lg = lane >> 4;
  const int fa = (wr * 64 + lr) * 32 + lg * 8;
  const int fb = (wc * 64 + lr) * 32 + lg * 8;

  f4_t acc[4][4];
#pragma unroll
  for (int i = 0; i < 4; ++i)
#pragma unroll
    for (int j = 0; j < 4; ++j) acc[i][j] = (f4_t)0.f;

  const int nt = K >> 5;
  int cur = 0;

  // stage tile into buffer b (4 gload_lds per wave)
  auto stage = [&](int b) {
    char* la = (char*)As + b * 8192 + wave * 1024;
    char* lb = (char*)Bs + b * 8192 + wave * 1024;
    gload16(pa0, la); gload16(pa1, la + 4096);
    gload16(pb0, lb); gload16(pb1, lb + 4096);
    pa0 += 32; pa1 += 32; pb0 += 32; pb1 += 32;
  };

  stage(0);
  asm volatile("s_waitcnt vmcnt(0)" ::: "memory");
  __builtin_amdgcn_s_barrier();

  for (int t = 0; t < nt; ++t) {
    const bool more = (t + 1 < nt);
    if (more) stage(cur ^ 1);  // issue next tile's loads before compute
    const unsigned short* ap = As + cur * 4096;
    const unsigned short* bp = Bs + cur * 4096;
    s8_t af[4], bf[4];
#pragma unroll
    for (int f = 0; f < 4; ++f) {
      af[f] = *(const s8_t*)(ap + fa + f * 512);
      bf[f] = *(const s8_t*)(bp + fb + f * 512);
    }
#pragma unroll
    for (int i = 0; i < 4; ++i)
#pragma unroll
      for (int j = 0; j < 4; ++j)
        acc[i][j] = __builtin_amdgcn_mfma_f32_16x16x32_bf16(af[i], bf[j], acc[i][j], 0, 0, 0);
    if (more) {
      asm volatile("s_waitcnt vmcnt(0)" ::: "memory");  // next-tile loads landed
      __builtin_amdgcn_s_barrier();                     // visible to all waves
    }
    cur ^= 1;
  }

#pragma unroll
  for (int i = 0; i < 4; ++i) {
    const int rbase = m0 + wr * 64 + i * 16 + lg * 4;
#pragma unroll
    for (int j = 0; j < 4; ++j) {
      const int col = n0 + wc * 64 + j * 16 + lr;
#pragma unroll
      for (int e = 0; e < 4; ++e) {
        const int row = rbase + e;
        float v = acc[i][j][e];
        if (BIAS_MODE == 1) v += bias[row];
        const long long off = (long long)bz * sC + (long long)row * ldc + col;
        if (RESID) v += resid[(long long)bz * sR + (long long)row * ldc + col];
        if (OUT_BF16) ((unsigned short*)Cp)[off] = f2bf(v);
        else          ((float*)Cp)[off] = v;
      }
    }
  }
}

// ---------- fused triple softmax ----------
__device__ __forceinline__ float wave_red_max(float v) {
#pragma unroll
  for (int o = 32; o > 0; o >>= 1) v = fmaxf(v, __shfl_down(v, o, 64));
  return v;
}
__device__ __forceinline__ float wave_red_sum(float v) {
#pragma unroll
  for (int o = 32; o > 0; o >>= 1) v += __shfl_down(v, o, 64);
  return v;
}
__device__ __forceinline__ float block_red_max(float v, float* red) {
  v = wave_red_max(v);
  if ((threadIdx.x & 63) == 0) red[threadIdx.x >> 6] = v;
  __syncthreads();
  v = fmaxf(fmaxf(red[0], red[1]), fmaxf(red[2], red[3]));
  __syncthreads();
  return v;
}
__device__ __forceinline__ float block_red_sum(float v, float* red) {
  v = wave_red_sum(v);
  if ((threadIdx.x & 63) == 0) red[threadIdx.x >> 6] = v;
  __syncthreads();
  v = red[0] + red[1] + red[2] + red[3];
  __syncthreads();
  return v;
}

__global__ __launch_bounds__(256) void k_combine(float* __restrict__ ec,
                                                 const float* __restrict__ es) {
  __shared__ float red[4];
  const size_t row = blockIdx.x;
  float* cp = ec + row * 1024;
  const float* sp = es + row * 1024;
  const int tid = threadIdx.x;
  float4 c4 = ((const float4*)cp)[tid];
  float4 s4 = ((const float4*)sp)[tid];

  float mx = fmaxf(fmaxf(c4.x, c4.y), fmaxf(c4.z, c4.w));
  mx = block_red_max(mx, red);
  float e0 = __expf(c4.x - mx), e1 = __expf(c4.y - mx);
  float e2 = __expf(c4.z - mx), e3 = __expf(c4.w - mx);
  float sc = block_red_sum(e0 + e1 + e2 + e3, red);

  float t0 = -s4.x, t1 = -s4.y, t2 = -s4.z, t3 = -s4.w;
  float mt = fmaxf(fmaxf(t0, t1), fmaxf(t2, t3));
  mt = block_red_max(mt, red);
  float f0 = __expf(t0 - mt), f1 = __expf(t1 - mt);
  float f2 = __expf(t2 - mt), f3 = __expf(t3 - mt);
  float ss = block_red_sum(f0 + f1 + f2 + f3, red);

  const float rc = 1.f / sc, rs = 1.f / ss;
  float g0 = __expf((e0 * rc) * (f0 * rs));
  float g1 = __expf((e1 * rc) * (f1 * rs));
  float g2 = __expf((e2 * rc) * (f2 * rs));
  float g3 = __expf((e3 * rc) * (f3 * rs));
  float s3 = block_red_sum(g0 + g1 + g2 + g3, red);
  const float r3 = 1.f / s3;
  ushort4 o;
  o.x = f2bf(g0 * r3); o.y = f2bf(g1 * r3); o.z = f2bf(g2 * r3); o.w = f2bf(g3 * r3);
  ((ushort4*)cp)[tid] = o;
}

// ---------- launch ----------
extern "C" void kernel_launch(void* const* d_in, const int* in_sizes, int n_in,
                              void* d_out, int out_size, void* d_ws, size_t ws_size,
                              hipStream_t stream) {
  const float* z = (const float*)d_in[0];
  const float* x = (const float*)d_in[1];
  const float* y = (const float*)d_in[2];
  const float* Wq = (const float*)d_in[3];
  const float* bq = (const float*)d_in[4];
  const float* Wk = (const float*)d_in[5];
  const float* bk = (const float*)d_in[6];
  const float* Wv = (const float*)d_in[7];
  const float* bv = (const float*)d_in[8];
  float* out = (float*)d_out;

  // ws (288 MiB):
  // P01 [0,128M):   es fp32           -> after combine: z_t bf16 [0,64M) | v_bf [64M,128M)
  // P23 [128,256M): x_tf32 -> y_tf32 -> ec fp32 (attn bf16 in-place, row stride 2048)
  // P4  [256,288M): q_t fp32 16M | k_t fp32 16M -> after ec: wv bf16 2M
  char* ws = (char*)d_ws;
  float* es = (float*)ws;
  unsigned short* z_t = (unsigned short*)ws;
  unsigned short* v_bf = z_t + 33554432;
  char* wsB = ws + 134217728;
  float* xytf = (float*)wsB;           // x_tf32 then y_tf32
  float* ec = (float*)wsB;
  unsigned short* attn = (unsigned short*)wsB;
  char* wsC = ws + 268435456;
  float* q_t = (float*)wsC;            // [32][1024][128]
  float* k_t = q_t + 4194304;
  unsigned short* wv = (unsigned short*)wsC;

  dim3 blk(256);
  // x^T fp32 ; q_t[b][n][o] = x_t[n][:] . Wq[o][:] + bq[o]
  hipLaunchKernelGGL(k_transp32, dim3(16, 16, 32), blk, 0, stream, x, xytf);
  hipLaunchKernelGGL((k_mfma3<2>), dim3(8, 1, 32), blk, 0, stream,
                     xytf, 1024, 1048576LL, Wq, 1024, 0LL, q_t, 128, 131072LL, bq, 1024);
  // y^T fp32 ; k_t
  hipLaunchKernelGGL(k_transp32, dim3(16, 16, 32), blk, 0, stream, y, xytf);
  hipLaunchKernelGGL((k_mfma3<2>), dim3(8, 1, 32), blk, 0, stream,
                     xytf, 1024, 1048576LL, Wk, 1024, 0LL, k_t, 128, 131072LL, bk, 1024);
  // es[b][m][d] = x[m][:] . y[d][:]   (fp32 operands straight from d_in)
  hipLaunchKernelGGL((k_mfma3<0>), dim3(8, 8, 32), blk, 0, stream,
                     x, 1024, 1048576LL, y, 1024, 1048576LL, es, 1024, 1048576LL,
                     (const float*)nullptr, 1024);
  // ec[b][i][j] = q_t[i][:] . k_t[j][:]  (K=128) -> P23 (y_tf dead)
  hipLaunchKernelGGL((k_mfma3<0>), dim3(8, 8, 32), blk, 0, stream,
                     q_t, 128, 131072LL, k_t, 128, 131072LL, ec, 1024, 1048576LL,
                     (const float*)nullptr, 128);
  // triple softmax -> attn bf16 in-place in ec rows
  hipLaunchKernelGGL(k_combine, dim3(32768), blk, 0, stream, ec, es);
  // z^T bf16 -> P01 low (es dead) ; Wv bf16 -> P4 (q_t,k_t dead)
  hipLaunchKernelGGL(k_transpbf, dim3(16, 16, 32), blk, 0, stream, z, z_t);
  hipLaunchKernelGGL(k_convert, dim3(512), blk, 0, stream, Wv, wv, 1048576);
  // v[b][o][n] = Wv[o][:] . z_t[n][:] + bv[o] -> bf16
  hipLaunchKernelGGL((k_mfma<1, true, false>), dim3(8, 8, 32), blk, 0, stream,
                     wv, 1024, 0LL, z_t, 1024, 1048576LL, (void*)v_bf, 1024, 1048576LL,
                     bv, (const float*)nullptr, 0LL, 1024);
  // out[b][c][m] = z[b][c][m] + v[c][:] . attn[m][:]
  hipLaunchKernelGGL((k_mfma<0, false, true>), dim3(8, 8, 32), blk, 0, stream,
                     v_bf, 1024, 1048576LL, attn, 2048, 2097152LL, (void*)out, 1024, 1048576LL,
                     (const float*)nullptr, z, 1048576LL, 1024);
}

// Round 8
// 866.153 us; speedup vs baseline: 1.1596x; 1.0129x over previous
//
#include <hip/hip_runtime.h>
#include <hip/hip_bf16.h>

typedef __attribute__((ext_vector_type(8))) short s8_t;    // 8 x bf16 (4 VGPR)
typedef __attribute__((ext_vector_type(4))) float f4_t;    // MFMA accumulator

// ---------- helpers ----------
__device__ __forceinline__ unsigned short f2bf(float f) {
  union { float f; unsigned u; } x; x.f = f;
  unsigned r = x.u + 0x7fffu + ((x.u >> 16) & 1u);  // RNE
  return (unsigned short)(r >> 16);
}

// split fp32 pair -> packed bf16 hi pair + packed bf16 lo pair (truncation split:
// hi = top16(x), lo = top16(x - hi); dropped residual <= 2^-16 |x|)
__device__ __forceinline__ void split2(float e0, float e1, unsigned& hp, unsigned& lp) {
  unsigned b0 = __float_as_uint(e0), b1 = __float_as_uint(e1);
  unsigned h0 = b0 & 0xFFFF0000u, h1 = b1 & 0xFFFF0000u;
  hp = (b0 >> 16) | h1;
  float l0 = e0 - __uint_as_float(h0), l1 = e1 - __uint_as_float(h1);
  lp = (__float_as_uint(l0) >> 16) | (__float_as_uint(l1) & 0xFFFF0000u);
}

__device__ __forceinline__ void gload16(const void* g, void* l) {
  __builtin_amdgcn_global_load_lds(
      (const __attribute__((address_space(1))) void*)g,
      (__attribute__((address_space(3))) void*)l, 16, 0, 0);
}

// T1 XCD swizzle (nwg % 8 == 0 for all grids using this)
__device__ __forceinline__ void swz_grid(int& bx, int& by, int& bz) {
  const int gx = gridDim.x, gy = gridDim.y;
  const int nwg = gx * gy * gridDim.z;
  const int flat = (blockIdx.z * gy + blockIdx.y) * gx + blockIdx.x;
  const int s = (flat & 7) * (nwg >> 3) + (flat >> 3);
  bx = s % gx;
  const int r = s / gx;
  by = r % gy;
  bz = r / gy;
}

// ---------- fp32 -> bf16 elementwise convert (for Wv) ----------
__global__ __launch_bounds__(256) void k_convert(const float* __restrict__ in,
                                                 unsigned short* __restrict__ out, int n) {
  int i = (blockIdx.x * 256 + threadIdx.x) * 8;
  if (i >= n) return;
  float4 a = *(const float4*)(in + i);
  float4 b = *(const float4*)(in + i + 4);
  ushort4 u0; u0.x = f2bf(a.x); u0.y = f2bf(a.y); u0.z = f2bf(a.z); u0.w = f2bf(a.w);
  ushort4 u1; u1.x = f2bf(b.x); u1.y = f2bf(b.y); u1.z = f2bf(b.z); u1.w = f2bf(b.w);
  *(ushort4*)(out + i) = u0;
  *(ushort4*)(out + i + 4) = u1;
}

// ---------- fp32 [1024][1024]/batch -> fp32 transposed ----------
__global__ __launch_bounds__(256) void k_transp32(const float* __restrict__ in,
                                                  float* __restrict__ out) {
  __shared__ float tile[64][65];
  const int t = threadIdx.x, b = blockIdx.z;
  const int r0 = blockIdx.y * 64, c0 = blockIdx.x * 64;
  const float* ip = in + (size_t)b * 1048576;
  float* op = out + (size_t)b * 1048576;
  const int tr = t >> 4, tc = (t & 15) * 4;
#pragma unroll
  for (int p = 0; p < 4; ++p) {
    int r = p * 16 + tr;
    float4 v = *(const float4*)(ip + (size_t)(r0 + r) * 1024 + c0 + tc);
    tile[r][tc] = v.x; tile[r][tc + 1] = v.y; tile[r][tc + 2] = v.z; tile[r][tc + 3] = v.w;
  }
  __syncthreads();
#pragma unroll
  for (int p = 0; p < 4; ++p) {
    int n = p * 16 + tr;
    float4 w;
    w.x = tile[tc][n]; w.y = tile[tc + 1][n]; w.z = tile[tc + 2][n]; w.w = tile[tc + 3][n];
    *(float4*)(op + (size_t)(c0 + n) * 1024 + r0 + tc) = w;
  }
}

// ---------- fp32 [1024][1024]/batch -> bf16 transposed (for z) ----------
__global__ __launch_bounds__(256) void k_transpbf(const float* __restrict__ in,
                                                  unsigned short* __restrict__ outt) {
  __shared__ unsigned short tile[64][72];
  const int t = threadIdx.x, b = blockIdx.z;
  const int r0 = blockIdx.y * 64, c0 = blockIdx.x * 64;
  const float* ip = in + (size_t)b * 1048576;
  const int tr = t >> 4, tc = (t & 15) * 4;
#pragma unroll
  for (int p = 0; p < 4; ++p) {
    int r = p * 16 + tr;
    float4 v = *(const float4*)(ip + (size_t)(r0 + r) * 1024 + c0 + tc);
    tile[r][tc] = f2bf(v.x); tile[r][tc + 1] = f2bf(v.y);
    tile[r][tc + 2] = f2bf(v.z); tile[r][tc + 3] = f2bf(v.w);
  }
  __syncthreads();
#pragma unroll
  for (int p = 0; p < 4; ++p) {
    int n = p * 16 + tr;
    ushort4 w;
    w.x = tile[tc][n]; w.y = tile[tc + 1][n]; w.z = tile[tc + 2][n]; w.w = tile[tc + 3][n];
    *(ushort4*)(outt + (size_t)b * 1048576 + (size_t)(c0 + n) * 1024 + r0 + tc) = w;
  }
}

// split + write one 32-fp32 stripe (16 A + 16 B) into the 4 planes of buf
__device__ __forceinline__ void split_write(unsigned short* buf, int wbase,
                                            const float* av, const float* bv) {
  unsigned ah[8], al[8], bh[8], bl[8];
#pragma unroll
  for (int p = 0; p < 8; ++p) {
    split2(av[2 * p], av[2 * p + 1], ah[p], al[p]);
    split2(bv[2 * p], bv[2 * p + 1], bh[p], bl[p]);
  }
  *(uint4*)(buf + wbase) = *(uint4*)(ah);
  *(uint4*)(buf + wbase + 8) = *(uint4*)(ah + 4);
  *(uint4*)(buf + 4096 + wbase) = *(uint4*)(al);
  *(uint4*)(buf + 4096 + wbase + 8) = *(uint4*)(al + 4);
  *(uint4*)(buf + 8192 + wbase) = *(uint4*)(bh);
  *(uint4*)(buf + 8192 + wbase + 8) = *(uint4*)(bh + 4);
  *(uint4*)(buf + 12288 + wbase) = *(uint4*)(bl);
  *(uint4*)(buf + 12288 + wbase + 8) = *(uint4*)(bl + 4);
}

// ---------- split-bf16 3-term MFMA GEMM, fp32 operands (round-3 proven) ----------
// C[m][n] = sum_k A[m][k]*B[n][k]; acc += Ah*Bh + Ah*Bl + Al*Bh. 128x128, BK=32.
// + T1 XCD swizzle (L2 locality for the latency-critical reg-staged loads).
// BIAS_MODE: 0 none, 2 bias[col]. Output fp32.
template <int BIAS_MODE>
__global__ __launch_bounds__(256) void k_mfma3(
    const float* __restrict__ A, int lda, long long sA,
    const float* __restrict__ B, int ldb, long long sB,
    float* __restrict__ C, int ldc, long long sC,
    const float* __restrict__ bias, int K) {
  __shared__ __align__(16) unsigned short sm[16384];  // Ah Al Bh Bl planes
  int bxs, bys, bz; swz_grid(bxs, bys, bz);
  const int tid = threadIdx.x;
  const int lane = tid & 63, wave = tid >> 6;
  const int wr = wave >> 1, wc = wave & 1;
  const int m0 = bxs * 128, n0 = bys * 128;

  const int sr = tid >> 1, sh = (tid & 1) * 16;
  const float* ag = A + (long long)bz * sA + (long long)(m0 + sr) * lda + sh;
  const float* bg = B + (long long)bz * sB + (long long)(n0 + sr) * ldb + sh;
  const int wbase = sr * 32 + sh;

  const int lr = lane & 15, lg = lane >> 4;
  const int fa = (wr * 64 + lr) * 32 + lg * 8;
  const int fb = (wc * 64 + lr) * 32 + lg * 8;

  f4_t acc[4][4];
#pragma unroll
  for (int i = 0; i < 4; ++i)
#pragma unroll
    for (int j = 0; j < 4; ++j) acc[i][j] = (f4_t)0.f;

  for (int k0 = 0; k0 < K; k0 += 32) {
    float av[16], bv[16];
#pragma unroll
    for (int p = 0; p < 4; ++p) {
      *(float4*)(av + p * 4) = *(const float4*)(ag + p * 4);
      *(float4*)(bv + p * 4) = *(const float4*)(bg + p * 4);
    }
    split_write(sm, wbase, av, bv);
    ag += 32; bg += 32;
    __syncthreads();
    const unsigned short* Ahp = sm;
    const unsigned short* Alp = sm + 4096;
    const unsigned short* Bhp = sm + 8192;
    const unsigned short* Blp = sm + 12288;
    s8_t fah[4], fbh[4], ftmp[4];
#pragma unroll
    for (int f = 0; f < 4; ++f) {
      fah[f] = *(const s8_t*)(Ahp + fa + f * 512);
      fbh[f] = *(const s8_t*)(Bhp + fb + f * 512);
    }
#pragma unroll
    for (int i = 0; i < 4; ++i)
#pragma unroll
      for (int j = 0; j < 4; ++j)
        acc[i][j] = __builtin_amdgcn_mfma_f32_16x16x32_bf16(fah[i], fbh[j], acc[i][j], 0, 0, 0);
#pragma unroll
    for (int f = 0; f < 4; ++f) ftmp[f] = *(const s8_t*)(Blp + fb + f * 512);
#pragma unroll
    for (int i = 0; i < 4; ++i)
#pragma unroll
      for (int j = 0; j < 4; ++j)
        acc[i][j] = __builtin_amdgcn_mfma_f32_16x16x32_bf16(fah[i], ftmp[j], acc[i][j], 0, 0, 0);
#pragma unroll
    for (int f = 0; f < 4; ++f) ftmp[f] = *(const s8_t*)(Alp + fa + f * 512);
#pragma unroll
    for (int i = 0; i < 4; ++i)
#pragma unroll
      for (int j = 0; j < 4; ++j)
        acc[i][j] = __builtin_amdgcn_mfma_f32_16x16x32_bf16(ftmp[i], fbh[j], acc[i][j], 0, 0, 0);
    __syncthreads();
  }

#pragma unroll
  for (int i = 0; i < 4; ++i) {
    const int rbase = m0 + wr * 64 + i * 16 + lg * 4;
#pragma unroll
    for (int j = 0; j < 4; ++j) {
      const int col = n0 + wc * 64 + j * 16 + lr;
      float bc = (BIAS_MODE == 2) ? bias[col] : 0.f;
#pragma unroll
      for (int e = 0; e < 4; ++e) {
        float v = acc[i][j][e];
        if (BIAS_MODE == 2) v += bc;
        C[(long long)bz * sC + (long long)(rbase + e) * ldc + col] = v;
      }
    }
  }
}

// ---------- bf16 NT MFMA GEMM, 3-buffer counted-vmcnt pipeline (T3+T4) ----------
// Iter t: stage(t+2) -> s_waitcnt vmcnt(8) [2 stages x 4 loads stay in flight;
// buf t's loads (issued at t-2, ~2 compute phases ago) are guaranteed landed]
// -> s_barrier -> ds_read frags + 16 MFMA -> s_barrier [protects buf (t%3) from
// being restaged at t+1]. sched_barrier(0) fences per rule 18. Requires K>=96.
// LDS 3 x (8KB A + 8KB B) = 48KB -> 3 blocks/CU.
template <int BIAS_MODE, bool OUT_BF16, bool RESID>
__global__ __launch_bounds__(256) void k_mfma(
    const unsigned short* __restrict__ A, int lda, long long sA,
    const unsigned short* __restrict__ B, int ldb, long long sB,
    void* __restrict__ Cp, int ldc, long long sC,
    const float* __restrict__ bias,
    const float* __restrict__ resid, long long sR, int K) {
  __shared__ __align__(16) unsigned short As[12288];  // 3 bufs x 4096
  __shared__ __align__(16) unsigned short Bs[12288];
  int bxs, bys, bz; swz_grid(bxs, bys, bz);
  const int tid = threadIdx.x;
  const int lane = tid & 63, wave = tid >> 6;
  const int wr = wave >> 1, wc = wave & 1;
  const int m0 = bxs * 128, n0 = bys * 128;

  const int ch0 = wave * 64 + lane, ch1 = ch0 + 256;
  const unsigned short* pa0 = A + (long long)bz * sA + (long long)(m0 + (ch0 >> 2)) * lda + (ch0 & 3) * 8;
  const unsigned short* pa1 = A + (long long)bz * sA + (long long)(m0 + (ch1 >> 2)) * lda + (ch1 & 3) * 8;
  const unsigned short* pb0 = B + (long long)bz * sB + (long long)(n0 + (ch0 >> 2)) * ldb + (ch0 & 3) * 8;
  const unsigned short* pb1 = B + (long long)bz * sB + (long long)(n0 + (ch1 >> 2)) * ldb + (ch1 & 3) * 8;

  const int lr = lane & 15, lg = lane >> 4;
  const int fa = (wr * 64 + lr) * 32 + lg * 8;
  const int fb = (wc * 64 + lr) * 32 + lg * 8;

  f4_t acc[4][4];
#pragma unroll
  for (int i = 0; i < 4; ++i)
#pragma unroll
    for (int j = 0; j < 4; ++j) acc[i][j] = (f4_t)0.f;

  // rotating buffer pointers (explicit rotation -> stays in scalar regs, rule 20)
  char* a0 = (char*)As; char* a1 = a0 + 8192; char* a2 = a0 + 16384;
  char* b0 = (char*)Bs; char* b1 = b0 + 8192; char* b2 = b0 + 16384;

  auto stage = [&](char* la, char* lb) {
    gload16(pa0, la + wave * 1024);
    gload16(pa1, la + 4096 + wave * 1024);
    gload16(pb0, lb + wave * 1024);
    gload16(pb1, lb + 4096 + wave * 1024);
    pa0 += 32; pa1 += 32; pb0 += 32; pb1 += 32;
  };

  const int nt = K >> 5;  // callers use K=1024 -> nt=32 (>= 3 required)
  stage(a0, b0);
  stage(a1, b1);

  for (int t = 0; t < nt; ++t) {
    if (t + 2 < nt) {
      stage(a2, b2);
      asm volatile("s_waitcnt vmcnt(8)" ::: "memory");   // keep newest 2 stages in flight
    } else if (t + 1 < nt) {
      asm volatile("s_waitcnt vmcnt(4)" ::: "memory");
    } else {
      asm volatile("s_waitcnt vmcnt(0)" ::: "memory");
    }
    __builtin_amdgcn_sched_barrier(0);
    __builtin_amdgcn_s_barrier();          // all waves' buf-t data visible
    __builtin_amdgcn_sched_barrier(0);
    const unsigned short* ap = (const unsigned short*)a0;
    const unsigned short* bp = (const unsigned short*)b0;
    s8_t af[4], bf[4];
#pragma unroll
    for (int f = 0; f < 4; ++f) {
      af[f] = *(const s8_t*)(ap + fa + f * 512);
      bf[f] = *(const s8_t*)(bp + fb + f * 512);
    }
#pragma unroll
    for (int i = 0; i < 4; ++i)
#pragma unroll
      for (int j = 0; j < 4; ++j)
        acc[i][j] = __builtin_amdgcn_mfma_f32_16x16x32_bf16(af[i], bf[j], acc[i][j], 0, 0, 0);
    __builtin_amdgcn_sched_barrier(0);
    __builtin_amdgcn_s_barrier();          // all waves done reading buf t
    __builtin_amdgcn_sched_barrier(0);
    char* ta = a0; a0 = a1; a1 = a2; a2 = ta;
    char* tb = b0; b0 = b1; b1 = b2; b2 = tb;
  }

#pragma unroll
  for (int i = 0; i < 4; ++i) {
    const int rbase = m0 + wr * 64 + i * 16 + lg * 4;
#pragma unroll
    for (int j = 0; j < 4; ++j) {
      const int col = n0 + wc * 64 + j * 16 + lr;
#pragma unroll
      for (int e = 0; e < 4; ++e) {
        const int row = rbase + e;
        float v = acc[i][j][e];
        if (BIAS_MODE == 1) v += bias[row];
        const long long off = (long long)bz * sC + (long long)row * ldc + col;
        if (RESID) v += resid[(long long)bz * sR + (long long)row * ldc + col];
        if (OUT_BF16) ((unsigned short*)Cp)[off] = f2bf(v);
        else          ((float*)Cp)[off] = v;
      }
    }
  }
}

// ---------- fused triple softmax ----------
__device__ __forceinline__ float wave_red_max(float v) {
#pragma unroll
  for (int o = 32; o > 0; o >>= 1) v = fmaxf(v, __shfl_down(v, o, 64));
  return v;
}
__device__ __forceinline__ float wave_red_sum(float v) {
#pragma unroll
  for (int o = 32; o > 0; o >>= 1) v += __shfl_down(v, o, 64);
  return v;
}
__device__ __forceinline__ float block_red_max(float v, float* red) {
  v = wave_red_max(v);
  if ((threadIdx.x & 63) == 0) red[threadIdx.x >> 6] = v;
  __syncthreads();
  v = fmaxf(fmaxf(red[0], red[1]), fmaxf(red[2], red[3]));
  __syncthreads();
  return v;
}
__device__ __forceinline__ float block_red_sum(float v, float* red) {
  v = wave_red_sum(v);
  if ((threadIdx.x & 63) == 0) red[threadIdx.x >> 6] = v;
  __syncthreads();
  v = red[0] + red[1] + red[2] + red[3];
  __syncthreads();
  return v;
}

__global__ __launch_bounds__(256) void k_combine(float* __restrict__ ec,
                                                 const float* __restrict__ es) {
  __shared__ float red[4];
  const size_t row = blockIdx.x;
  float* cp = ec + row * 1024;
  const float* sp = es + row * 1024;
  const int tid = threadIdx.x;
  float4 c4 = ((const float4*)cp)[tid];
  float4 s4 = ((const float4*)sp)[tid];

  float mx = fmaxf(fmaxf(c4.x, c4.y), fmaxf(c4.z, c4.w));
  mx = block_red_max(mx, red);
  float e0 = __expf(c4.x - mx), e1 = __expf(c4.y - mx);
  float e2 = __expf(c4.z - mx), e3 = __expf(c4.w - mx);
  float sc = block_red_sum(e0 + e1 + e2 + e3, red);

  float t0 = -s4.x, t1 = -s4.y, t2 = -s4.z, t3 = -s4.w;
  float mt = fmaxf(fmaxf(t0, t1), fmaxf(t2, t3));
  mt = block_red_max(mt, red);
  float f0 = __expf(t0 - mt), f1 = __expf(t1 - mt);
  float f2 = __expf(t2 - mt), f3 = __expf(t3 - mt);
  float ss = block_red_sum(f0 + f1 + f2 + f3, red);

  const float rc = 1.f / sc, rs = 1.f / ss;
  float g0 = __expf((e0 * rc) * (f0 * rs));
  float g1 = __expf((e1 * rc) * (f1 * rs));
  float g2 = __expf((e2 * rc) * (f2 * rs));
  float g3 = __expf((e3 * rc) * (f3 * rs));
  float s3 = block_red_sum(g0 + g1 + g2 + g3, red);
  const float r3 = 1.f / s3;
  ushort4 o;
  o.x = f2bf(g0 * r3); o.y = f2bf(g1 * r3); o.z = f2bf(g2 * r3); o.w = f2bf(g3 * r3);
  ((ushort4*)cp)[tid] = o;
}

// ---------- launch ----------
extern "C" void kernel_launch(void* const* d_in, const int* in_sizes, int n_in,
                              void* d_out, int out_size, void* d_ws, size_t ws_size,
                              hipStream_t stream) {
  const float* z = (const float*)d_in[0];
  const float* x = (const float*)d_in[1];
  const float* y = (const float*)d_in[2];
  const float* Wq = (const float*)d_in[3];
  const float* bq = (const float*)d_in[4];
  const float* Wk = (const float*)d_in[5];
  const float* bk = (const float*)d_in[6];
  const float* Wv = (const float*)d_in[7];
  const float* bv = (const float*)d_in[8];
  float* out = (float*)d_out;

  // ws (288 MiB):
  // P01 [0,128M):   es fp32           -> after combine: z_t bf16 [0,64M) | v_bf [64M,128M)
  // P23 [128,256M): x_tf32 -> y_tf32 -> ec fp32 (attn bf16 in-place, row stride 2048)
  // P4  [256,288M): q_t fp32 16M | k_t fp32 16M -> after ec: wv bf16 2M
  char* ws = (char*)d_ws;
  float* es = (float*)ws;
  unsigned short* z_t = (unsigned short*)ws;
  unsigned short* v_bf = z_t + 33554432;
  char* wsB = ws + 134217728;
  float* xytf = (float*)wsB;           // x_tf32 then y_tf32
  float* ec = (float*)wsB;
  unsigned short* attn = (unsigned short*)wsB;
  char* wsC = ws + 268435456;
  float* q_t = (float*)wsC;            // [32][1024][128]
  float* k_t = q_t + 4194304;
  unsigned short* wv = (unsigned short*)wsC;

  dim3 blk(256);
  // x^T fp32 ; q_t[b][n][o] = x_t[n][:] . Wq[o][:] + bq[o]
  hipLaunchKernelGGL(k_transp32, dim3(16, 16, 32), blk, 0, stream, x, xytf);
  hipLaunchKernelGGL((k_mfma3<2>), dim3(8, 1, 32), blk, 0, stream,
                     xytf, 1024, 1048576LL, Wq, 1024, 0LL, q_t, 128, 131072LL, bq, 1024);
  // y^T fp32 ; k_t
  hipLaunchKernelGGL(k_transp32, dim3(16, 16, 32), blk, 0, stream, y, xytf);
  hipLaunchKernelGGL((k_mfma3<2>), dim3(8, 1, 32), blk, 0, stream,
                     xytf, 1024, 1048576LL, Wk, 1024, 0LL, k_t, 128, 131072LL, bk, 1024);
  // es[b][m][d] = x[m][:] . y[d][:]   (fp32 operands straight from d_in)
  hipLaunchKernelGGL((k_mfma3<0>), dim3(8, 8, 32), blk, 0, stream,
                     x, 1024, 1048576LL, y, 1024, 1048576LL, es, 1024, 1048576LL,
                     (const float*)nullptr, 1024);
  // ec[b][i][j] = q_t[i][:] . k_t[j][:]  (K=128) -> P23 (y_tf dead)
  hipLaunchKernelGGL((k_mfma3<0>), dim3(8, 8, 32), blk, 0, stream,
                     q_t, 128, 131072LL, k_t, 128, 131072LL, ec, 1024, 1048576LL,
                     (const float*)nullptr, 128);
  // triple softmax -> attn bf16 in-place in ec rows
  hipLaunchKernelGGL(k_combine, dim3(32768), blk, 0, stream, ec, es);
  // z^T bf16 -> P01 low (es dead) ; Wv bf16 -> P4 (q_t,k_t dead)
  hipLaunchKernelGGL(k_transpbf, dim3(16, 16, 32), blk, 0, stream, z, z_t);
  hipLaunchKernelGGL(k_convert, dim3(512), blk, 0, stream, Wv, wv, 1048576);
  // v[b][o][n] = Wv[o][:] . z_t[n][:] + bv[o] -> bf16
  hipLaunchKernelGGL((k_mfma<1, true, false>), dim3(8, 8, 32), blk, 0, stream,
                     wv, 1024, 0LL, z_t, 1024, 1048576LL, (void*)v_bf, 1024, 1048576LL,
                     bv, (const float*)nullptr, 0LL, 1024);
  // out[b][c][m] = z[b][c][m] + v[c][:] . attn[m][:]
  hipLaunchKernelGGL((k_mfma<0, false, true>), dim3(8, 8, 32), blk, 0, stream,
                     v_bf, 1024, 1048576LL, attn, 2048, 2097152LL, (void*)out, 1024, 1048576LL,
                     (const float*)nullptr, z, 1048576LL, 1024);
}

// Round 9
// 796.604 us; speedup vs baseline: 1.2608x; 1.0873x over previous
//
#include <hip/hip_runtime.h>
#include <hip/hip_bf16.h>

typedef __attribute__((ext_vector_type(8))) short s8_t;    // 8 x bf16 (4 VGPR)
typedef __attribute__((ext_vector_type(4))) float f4_t;    // MFMA accumulator

// ---------- helpers ----------
__device__ __forceinline__ unsigned short f2bf(float f) {
  union { float f; unsigned u; } x; x.f = f;
  unsigned r = x.u + 0x7fffu + ((x.u >> 16) & 1u);  // RNE
  return (unsigned short)(r >> 16);
}

// truncation split, elementwise: hi = top16(v), lo = top16(v - hi)
__device__ __forceinline__ void split1(float v, unsigned short& h, unsigned short& l) {
  unsigned b = __float_as_uint(v);
  unsigned hb = b & 0xFFFF0000u;
  h = (unsigned short)(b >> 16);
  float lo = v - __uint_as_float(hb);
  l = (unsigned short)(__float_as_uint(lo) >> 16);
}

// pair split, packed (bit-identical per element to split1)
__device__ __forceinline__ void split2(float e0, float e1, unsigned& hp, unsigned& lp) {
  unsigned b0 = __float_as_uint(e0), b1 = __float_as_uint(e1);
  unsigned h0 = b0 & 0xFFFF0000u, h1 = b1 & 0xFFFF0000u;
  hp = (b0 >> 16) | h1;
  float l0 = e0 - __uint_as_float(h0), l1 = e1 - __uint_as_float(h1);
  lp = (__float_as_uint(l0) >> 16) | (__float_as_uint(l1) & 0xFFFF0000u);
}

__device__ __forceinline__ void gload16(const void* g, void* l) {
  __builtin_amdgcn_global_load_lds(
      (const __attribute__((address_space(1))) void*)g,
      (__attribute__((address_space(3))) void*)l, 16, 0, 0);
}

// T1 XCD swizzle (nwg % 8 == 0 for all grids using this)
__device__ __forceinline__ void swz_grid(int& bx, int& by, int& bz) {
  const int gx = gridDim.x, gy = gridDim.y;
  const int nwg = gx * gy * gridDim.z;
  const int flat = (blockIdx.z * gy + blockIdx.y) * gx + blockIdx.x;
  const int s = (flat & 7) * (nwg >> 3) + (flat >> 3);
  bx = s % gx;
  const int r = s / gx;
  by = r % gy;
  bz = r / gy;
}

// ---------- fp32 -> bf16 convert (Wv) ----------
__global__ __launch_bounds__(256) void k_convert(const float* __restrict__ in,
                                                 unsigned short* __restrict__ out, int n) {
  int i = (blockIdx.x * 256 + threadIdx.x) * 8;
  if (i >= n) return;
  float4 a = *(const float4*)(in + i);
  float4 b = *(const float4*)(in + i + 4);
  ushort4 u0; u0.x = f2bf(a.x); u0.y = f2bf(a.y); u0.z = f2bf(a.z); u0.w = f2bf(a.w);
  ushort4 u1; u1.x = f2bf(b.x); u1.y = f2bf(b.y); u1.z = f2bf(b.z); u1.w = f2bf(b.w);
  *(ushort4*)(out + i) = u0;
  *(ushort4*)(out + i + 4) = u1;
}

// ---------- fp32 [1024][1024]/batch -> TRANSPOSED hi/lo bf16 planes ----------
__global__ __launch_bounds__(256) void k_tsplitT(const float* __restrict__ in,
                                                 unsigned short* __restrict__ th,
                                                 unsigned short* __restrict__ tl) {
  __shared__ float tile[64][65];
  const int t = threadIdx.x, bz = blockIdx.z;
  const int r0 = blockIdx.y * 64, c0 = blockIdx.x * 64;
  const float* ip = in + (size_t)bz * 1048576;
  const size_t ob = (size_t)bz * 1048576;
  const int tr = t >> 4, tc = (t & 15) * 4;
#pragma unroll
  for (int p = 0; p < 4; ++p) {
    int r = p * 16 + tr;
    float4 v = *(const float4*)(ip + (size_t)(r0 + r) * 1024 + c0 + tc);
    tile[r][tc] = v.x; tile[r][tc + 1] = v.y; tile[r][tc + 2] = v.z; tile[r][tc + 3] = v.w;
  }
  __syncthreads();
#pragma unroll
  for (int p = 0; p < 4; ++p) {
    int n = p * 16 + tr;
    float a = tile[tc][n], b = tile[tc + 1][n], c = tile[tc + 2][n], d = tile[tc + 3][n];
    ushort4 h, l;
    split1(a, h.x, l.x); split1(b, h.y, l.y); split1(c, h.z, l.z); split1(d, h.w, l.w);
    *(ushort4*)(th + ob + (size_t)(c0 + n) * 1024 + r0 + tc) = h;
    *(ushort4*)(tl + ob + (size_t)(c0 + n) * 1024 + r0 + tc) = l;
  }
}

// ---------- fp32 [1024][1024]/batch -> bf16 transposed (for z) ----------
__global__ __launch_bounds__(256) void k_transpbf(const float* __restrict__ in,
                                                  unsigned short* __restrict__ outt) {
  __shared__ unsigned short tile[64][72];
  const int t = threadIdx.x, b = blockIdx.z;
  const int r0 = blockIdx.y * 64, c0 = blockIdx.x * 64;
  const float* ip = in + (size_t)b * 1048576;
  const int tr = t >> 4, tc = (t & 15) * 4;
#pragma unroll
  for (int p = 0; p < 4; ++p) {
    int r = p * 16 + tr;
    float4 v = *(const float4*)(ip + (size_t)(r0 + r) * 1024 + c0 + tc);
    tile[r][tc] = f2bf(v.x); tile[r][tc + 1] = f2bf(v.y);
    tile[r][tc + 2] = f2bf(v.z); tile[r][tc + 3] = f2bf(v.w);
  }
  __syncthreads();
#pragma unroll
  for (int p = 0; p < 4; ++p) {
    int n = p * 16 + tr;
    ushort4 w;
    w.x = tile[tc][n]; w.y = tile[tc + 1][n]; w.z = tile[tc + 2][n]; w.w = tile[tc + 3][n];
    *(ushort4*)(outt + (size_t)b * 1048576 + (size_t)(c0 + n) * 1024 + r0 + tc) = w;
  }
}

// split + write one 32-fp32 stripe (16 A + 16 B) into the 4 planes of buf
__device__ __forceinline__ void split_write(unsigned short* buf, int wbase,
                                            const float* av, const float* bv) {
  unsigned ah[8], al[8], bh[8], bl[8];
#pragma unroll
  for (int p = 0; p < 8; ++p) {
    split2(av[2 * p], av[2 * p + 1], ah[p], al[p]);
    split2(bv[2 * p], bv[2 * p + 1], bh[p], bl[p]);
  }
  *(uint4*)(buf + wbase) = *(uint4*)(ah);
  *(uint4*)(buf + wbase + 8) = *(uint4*)(ah + 4);
  *(uint4*)(buf + 4096 + wbase) = *(uint4*)(al);
  *(uint4*)(buf + 4096 + wbase + 8) = *(uint4*)(al + 4);
  *(uint4*)(buf + 8192 + wbase) = *(uint4*)(bh);
  *(uint4*)(buf + 8192 + wbase + 8) = *(uint4*)(bh + 4);
  *(uint4*)(buf + 12288 + wbase) = *(uint4*)(bl);
  *(uint4*)(buf + 12288 + wbase + 8) = *(uint4*)(bl + 4);
}

// ---------- split-bf16 3-term MFMA GEMM, fp32 operands (r3-proven, r8 swizzle) ----------
// Used for es (K=1024) and ec (K=128). BIAS_MODE: 0 none. Output fp32.
template <int BIAS_MODE>
__global__ __launch_bounds__(256) void k_mfma3(
    const float* __restrict__ A, int lda, long long sA,
    const float* __restrict__ B, int ldb, long long sB,
    float* __restrict__ C, int ldc, long long sC,
    const float* __restrict__ bias, int K) {
  __shared__ __align__(16) unsigned short sm[16384];  // Ah Al Bh Bl planes
  int bxs, bys, bz; swz_grid(bxs, bys, bz);
  const int tid = threadIdx.x;
  const int lane = tid & 63, wave = tid >> 6;
  const int wr = wave >> 1, wc = wave & 1;
  const int m0 = bxs * 128, n0 = bys * 128;

  const int sr = tid >> 1, sh = (tid & 1) * 16;
  const float* ag = A + (long long)bz * sA + (long long)(m0 + sr) * lda + sh;
  const float* bg = B + (long long)bz * sB + (long long)(n0 + sr) * ldb + sh;
  const int wbase = sr * 32 + sh;

  const int lr = lane & 15, lg = lane >> 4;
  const int fa = (wr * 64 + lr) * 32 + lg * 8;
  const int fb = (wc * 64 + lr) * 32 + lg * 8;

  f4_t acc[4][4];
#pragma unroll
  for (int i = 0; i < 4; ++i)
#pragma unroll
    for (int j = 0; j < 4; ++j) acc[i][j] = (f4_t)0.f;

  for (int k0 = 0; k0 < K; k0 += 32) {
    float av[16], bv[16];
#pragma unroll
    for (int p = 0; p < 4; ++p) {
      *(float4*)(av + p * 4) = *(const float4*)(ag + p * 4);
      *(float4*)(bv + p * 4) = *(const float4*)(bg + p * 4);
    }
    split_write(sm, wbase, av, bv);
    ag += 32; bg += 32;
    __syncthreads();
    const unsigned short* Ahp = sm;
    const unsigned short* Alp = sm + 4096;
    const unsigned short* Bhp = sm + 8192;
    const unsigned short* Blp = sm + 12288;
    s8_t fah[4], fbh[4], ftmp[4];
#pragma unroll
    for (int f = 0; f < 4; ++f) {
      fah[f] = *(const s8_t*)(Ahp + fa + f * 512);
      fbh[f] = *(const s8_t*)(Bhp + fb + f * 512);
    }
#pragma unroll
    for (int i = 0; i < 4; ++i)
#pragma unroll
      for (int j = 0; j < 4; ++j)
        acc[i][j] = __builtin_amdgcn_mfma_f32_16x16x32_bf16(fah[i], fbh[j], acc[i][j], 0, 0, 0);
#pragma unroll
    for (int f = 0; f < 4; ++f) ftmp[f] = *(const s8_t*)(Blp + fb + f * 512);
#pragma unroll
    for (int i = 0; i < 4; ++i)
#pragma unroll
      for (int j = 0; j < 4; ++j)
        acc[i][j] = __builtin_amdgcn_mfma_f32_16x16x32_bf16(fah[i], ftmp[j], acc[i][j], 0, 0, 0);
#pragma unroll
    for (int f = 0; f < 4; ++f) ftmp[f] = *(const s8_t*)(Alp + fa + f * 512);
#pragma unroll
    for (int i = 0; i < 4; ++i)
#pragma unroll
      for (int j = 0; j < 4; ++j)
        acc[i][j] = __builtin_amdgcn_mfma_f32_16x16x32_bf16(ftmp[i], fbh[j], acc[i][j], 0, 0, 0);
    __syncthreads();
  }

#pragma unroll
  for (int i = 0; i < 4; ++i) {
    const int rbase = m0 + wr * 64 + i * 16 + lg * 4;
#pragma unroll
    for (int j = 0; j < 4; ++j) {
      const int col = n0 + wc * 64 + j * 16 + lr;
      float bc = (BIAS_MODE == 2) ? bias[col] : 0.f;
#pragma unroll
      for (int e = 0; e < 4; ++e) {
        float v = acc[i][j][e];
        if (BIAS_MODE == 2) v += bc;
        C[(long long)bz * sC + (long long)(rbase + e) * ldc + col] = v;
      }
    }
  }
}

// ---------- merged q/k projection (r6-validated structure, fp32 output) ----------
// grid (8, 2, 32): by=0 -> q, by=1 -> k. A = transposed input hi/lo planes
// (gload_lds); B = Wq/Wk fp32 reg-staged split; out fp32 [n][128] + bias[col].
__global__ __launch_bounds__(256) void k_qk3p(
    const unsigned short* __restrict__ Axh, const unsigned short* __restrict__ Axl,
    const unsigned short* __restrict__ Ayh, const unsigned short* __restrict__ Ayl,
    const float* __restrict__ Wqf, const float* __restrict__ Wkf,
    const float* __restrict__ bqf, const float* __restrict__ bkf,
    float* __restrict__ Qt, float* __restrict__ Kt) {
  __shared__ __align__(16) unsigned short smAh[4096], smAl[4096], smBh[4096], smBl[4096];
  int bx, by, bz; swz_grid(bx, by, bz);
  const unsigned short* Ah = by ? Ayh : Axh;
  const unsigned short* Al = by ? Ayl : Axl;
  const float* Bf = by ? Wkf : Wqf;
  const float* bias = by ? bkf : bqf;
  float* Of = by ? Kt : Qt;

  const int tid = threadIdx.x, lane = tid & 63, wave = tid >> 6;
  const int wr = wave >> 1, wc = wave & 1;
  const int m0 = bx * 128;

  const int ch0 = wave * 64 + lane, ch1 = ch0 + 256;
  const int r0 = ch0 >> 2, kc0 = (ch0 & 3) * 8, r1 = ch1 >> 2, kc1 = (ch1 & 3) * 8;
  const unsigned short* pah0 = Ah + (long long)bz * 1048576 + (long long)(m0 + r0) * 1024 + kc0;
  const unsigned short* pah1 = Ah + (long long)bz * 1048576 + (long long)(m0 + r1) * 1024 + kc1;
  const unsigned short* pal0 = Al + (long long)bz * 1048576 + (long long)(m0 + r0) * 1024 + kc0;
  const unsigned short* pal1 = Al + (long long)bz * 1048576 + (long long)(m0 + r1) * 1024 + kc1;
  char* dAh0 = (char*)smAh + wave * 1024; char* dAh1 = dAh0 + 4096;
  char* dAl0 = (char*)smAl + wave * 1024; char* dAl1 = dAl0 + 4096;

  const int sr = tid >> 1, sh = (tid & 1) * 16;
  const float* bg = Bf + (long long)sr * 1024 + sh;
  const int wbase = sr * 32 + sh;

  const int lr = lane & 15, lg = lane >> 4;
  const int fa = (wr * 64 + lr) * 32 + lg * 8;
  const int fb = (wc * 64 + lr) * 32 + lg * 8;

  f4_t acc[4][4];
#pragma unroll
  for (int i = 0; i < 4; ++i)
#pragma unroll
    for (int j = 0; j < 4; ++j) acc[i][j] = (f4_t)0.f;

  for (int k0 = 0; k0 < 1024; k0 += 32) {
    gload16(pah0, dAh0); gload16(pah1, dAh1);
    gload16(pal0, dAl0); gload16(pal1, dAl1);
    pah0 += 32; pah1 += 32; pal0 += 32; pal1 += 32;
    float bv[16];
#pragma unroll
    for (int p = 0; p < 4; ++p) *(float4*)(bv + p * 4) = *(const float4*)(bg + p * 4);
    bg += 32;
    unsigned bh[8], bl[8];
#pragma unroll
    for (int p = 0; p < 8; ++p) split2(bv[2 * p], bv[2 * p + 1], bh[p], bl[p]);
    *(uint4*)(smBh + wbase) = *(uint4*)(bh);
    *(uint4*)(smBh + wbase + 8) = *(uint4*)(bh + 4);
    *(uint4*)(smBl + wbase) = *(uint4*)(bl);
    *(uint4*)(smBl + wbase + 8) = *(uint4*)(bl + 4);
    __syncthreads();
    s8_t fah[4], fbh[4], ft[4];
#pragma unroll
    for (int f = 0; f < 4; ++f) {
      fah[f] = *(const s8_t*)(smAh + fa + f * 512);
      fbh[f] = *(const s8_t*)(smBh + fb + f * 512);
    }
#pragma unroll
    for (int i = 0; i < 4; ++i)
#pragma unroll
      for (int j = 0; j < 4; ++j)
        acc[i][j] = __builtin_amdgcn_mfma_f32_16x16x32_bf16(fah[i], fbh[j], acc[i][j], 0, 0, 0);
#pragma unroll
    for (int f = 0; f < 4; ++f) ft[f] = *(const s8_t*)(smBl + fb + f * 512);
#pragma unroll
    for (int i = 0; i < 4; ++i)
#pragma unroll
      for (int j = 0; j < 4; ++j)
        acc[i][j] = __builtin_amdgcn_mfma_f32_16x16x32_bf16(fah[i], ft[j], acc[i][j], 0, 0, 0);
#pragma unroll
    for (int f = 0; f < 4; ++f) ft[f] = *(const s8_t*)(smAl + fa + f * 512);
#pragma unroll
    for (int i = 0; i < 4; ++i)
#pragma unroll
      for (int j = 0; j < 4; ++j)
        acc[i][j] = __builtin_amdgcn_mfma_f32_16x16x32_bf16(ft[i], fbh[j], acc[i][j], 0, 0, 0);
    __syncthreads();
  }

#pragma unroll
  for (int i = 0; i < 4; ++i) {
    const int rbase = m0 + wr * 64 + i * 16 + lg * 4;
#pragma unroll
    for (int j = 0; j < 4; ++j) {
      const int col = wc * 64 + j * 16 + lr;
      const float bc = bias[col];
#pragma unroll
      for (int e = 0; e < 4; ++e)
        Of[(long long)bz * 131072 + (long long)(rbase + e) * 128 + col] = acc[i][j][e] + bc;
    }
  }
}

// ---------- bf16 NT MFMA GEMM, 256x256 tile, 8 waves, 3-buffer counted vmcnt ----------
// Per iter t: stage(t+2) -> vmcnt(8) [2 stages x 4 loads in flight; stage-t landed]
// -> s_barrier -> frags + 32 MFMA/wave -> s_barrier -> rotate. LDS 96KB, 1 blk/CU.
template <int BIAS_MODE, bool OUT_BF16, bool RESID>
__global__ __launch_bounds__(512) void k_mfma256(
    const unsigned short* __restrict__ A, int lda, long long sA,
    const unsigned short* __restrict__ B, int ldb, long long sB,
    void* __restrict__ Cp, int ldc, long long sC,
    const float* __restrict__ bias,
    const float* __restrict__ resid, long long sR, int K) {
  __shared__ __align__(16) unsigned short As[24576];  // 3 bufs x 8192 (256x32)
  __shared__ __align__(16) unsigned short Bs[24576];  // 3 bufs x 8192 (256x32)
  int bxs, bys, bz; swz_grid(bxs, bys, bz);
  const int tid = threadIdx.x;
  const int lane = tid & 63, wave = tid >> 6;        // 8 waves
  const int wr = wave >> 2, wc = wave & 3;           // 2 x 4 -> wave tile 128x64
  const int m0 = bxs * 256, n0 = bys * 256;

  // staging: 1024 chunks of 16B per operand; thread stages chunks tid, tid+512
  const int cA0 = tid, cA1 = tid + 512;
  const unsigned short* pa0 = A + (long long)bz * sA + (long long)(m0 + (cA0 >> 2)) * lda + (cA0 & 3) * 8;
  const unsigned short* pa1 = A + (long long)bz * sA + (long long)(m0 + (cA1 >> 2)) * lda + (cA1 & 3) * 8;
  const unsigned short* pb0 = B + (long long)bz * sB + (long long)(n0 + (cA0 >> 2)) * ldb + (cA0 & 3) * 8;
  const unsigned short* pb1 = B + (long long)bz * sB + (long long)(n0 + (cA1 >> 2)) * ldb + (cA1 & 3) * 8;

  const int lr = lane & 15, lg = lane >> 4;
  const int fa = (wr * 128 + lr) * 32 + lg * 8;  // + i*512 per 16-row block (i<8)
  const int fb = (wc * 64 + lr) * 32 + lg * 8;   // + j*512 per 16-col block (j<4)

  f4_t acc[8][4];
#pragma unroll
  for (int i = 0; i < 8; ++i)
#pragma unroll
    for (int j = 0; j < 4; ++j) acc[i][j] = (f4_t)0.f;

  unsigned short* a0 = As; unsigned short* a1 = As + 8192; unsigned short* a2 = As + 16384;
  unsigned short* b0 = Bs; unsigned short* b1 = Bs + 8192; unsigned short* b2 = Bs + 16384;

  auto stage = [&](unsigned short* la, unsigned short* lb) {
    gload16(pa0, (char*)la + wave * 1024);
    gload16(pa1, (char*)la + 8192 + wave * 1024);
    gload16(pb0, (char*)lb + wave * 1024);
    gload16(pb1, (char*)lb + 8192 + wave * 1024);
    pa0 += 32; pa1 += 32; pb0 += 32; pb1 += 32;
  };

  const int nt = K >> 5;  // K=1024 -> 32 (>= 3 required)
  stage(a0, b0);
  stage(a1, b1);

  for (int t = 0; t < nt; ++t) {
    if (t + 2 < nt) {
      stage(a2, b2);
      asm volatile("s_waitcnt vmcnt(8)" ::: "memory");   // 2 newest stages stay in flight
    } else if (t + 1 < nt) {
      asm volatile("s_waitcnt vmcnt(4)" ::: "memory");
    } else {
      asm volatile("s_waitcnt vmcnt(0)" ::: "memory");
    }
    __builtin_amdgcn_sched_barrier(0);
    __builtin_amdgcn_s_barrier();
    __builtin_amdgcn_sched_barrier(0);
    const unsigned short* ap = a0;
    const unsigned short* bp = b0;
    s8_t af[8], bf[4];
#pragma unroll
    for (int i = 0; i < 8; ++i) af[i] = *(const s8_t*)(ap + fa + i * 512);
#pragma unroll
    for (int j = 0; j < 4; ++j) bf[j] = *(const s8_t*)(bp + fb + j * 512);
#pragma unroll
    for (int i = 0; i < 8; ++i)
#pragma unroll
      for (int j = 0; j < 4; ++j)
        acc[i][j] = __builtin_amdgcn_mfma_f32_16x16x32_bf16(af[i], bf[j], acc[i][j], 0, 0, 0);
    __builtin_amdgcn_sched_barrier(0);
    __builtin_amdgcn_s_barrier();
    __builtin_amdgcn_sched_barrier(0);
    unsigned short* ta = a0; a0 = a1; a1 = a2; a2 = ta;
    unsigned short* tb = b0; b0 = b1; b1 = b2; b2 = tb;
  }

#pragma unroll
  for (int i = 0; i < 8; ++i) {
    const int rbase = m0 + wr * 128 + i * 16 + lg * 4;
#pragma unroll
    for (int j = 0; j < 4; ++j) {
      const int col = n0 + wc * 64 + j * 16 + lr;
#pragma unroll
      for (int e = 0; e < 4; ++e) {
        const int row = rbase + e;
        float v = acc[i][j][e];
        if (BIAS_MODE == 1) v += bias[row];
        const long long off = (long long)bz * sC + (long long)row * ldc + col;
        if (RESID) v += resid[(long long)bz * sR + (long long)row * ldc + col];
        if (OUT_BF16) ((unsigned short*)Cp)[off] = f2bf(v);
        else          ((float*)Cp)[off] = v;
      }
    }
  }
}

// ---------- fused triple softmax ----------
__device__ __forceinline__ float wave_red_max(float v) {
#pragma unroll
  for (int o = 32; o > 0; o >>= 1) v = fmaxf(v, __shfl_down(v, o, 64));
  return v;
}
__device__ __forceinline__ float wave_red_sum(float v) {
#pragma unroll
  for (int o = 32; o > 0; o >>= 1) v += __shfl_down(v, o, 64);
  return v;
}
__device__ __forceinline__ float block_red_max(float v, float* red) {
  v = wave_red_max(v);
  if ((threadIdx.x & 63) == 0) red[threadIdx.x >> 6] = v;
  __syncthreads();
  v = fmaxf(fmaxf(red[0], red[1]), fmaxf(red[2], red[3]));
  __syncthreads();
  return v;
}
__device__ __forceinline__ float block_red_sum(float v, float* red) {
  v = wave_red_sum(v);
  if ((threadIdx.x & 63) == 0) red[threadIdx.x >> 6] = v;
  __syncthreads();
  v = red[0] + red[1] + red[2] + red[3];
  __syncthreads();
  return v;
}

__global__ __launch_bounds__(256) void k_combine(float* __restrict__ ec,
                                                 const float* __restrict__ es) {
  __shared__ float red[4];
  const size_t row = blockIdx.x;
  float* cp = ec + row * 1024;
  const float* sp = es + row * 1024;
  const int tid = threadIdx.x;
  float4 c4 = ((const float4*)cp)[tid];
  float4 s4 = ((const float4*)sp)[tid];

  float mx = fmaxf(fmaxf(c4.x, c4.y), fmaxf(c4.z, c4.w));
  mx = block_red_max(mx, red);
  float e0 = __expf(c4.x - mx), e1 = __expf(c4.y - mx);
  float e2 = __expf(c4.z - mx), e3 = __expf(c4.w - mx);
  float sc = block_red_sum(e0 + e1 + e2 + e3, red);

  float t0 = -s4.x, t1 = -s4.y, t2 = -s4.z, t3 = -s4.w;
  float mt = fmaxf(fmaxf(t0, t1), fmaxf(t2, t3));
  mt = block_red_max(mt, red);
  float f0 = __expf(t0 - mt), f1 = __expf(t1 - mt);
  float f2 = __expf(t2 - mt), f3 = __expf(t3 - mt);
  float ss = block_red_sum(f0 + f1 + f2 + f3, red);

  const float rc = 1.f / sc, rs = 1.f / ss;
  float g0 = __expf((e0 * rc) * (f0 * rs));
  float g1 = __expf((e1 * rc) * (f1 * rs));
  float g2 = __expf((e2 * rc) * (f2 * rs));
  float g3 = __expf((e3 * rc) * (f3 * rs));
  float s3 = block_red_sum(g0 + g1 + g2 + g3, red);
  const float r3 = 1.f / s3;
  ushort4 o;
  o.x = f2bf(g0 * r3); o.y = f2bf(g1 * r3); o.z = f2bf(g2 * r3); o.w = f2bf(g3 * r3);
  ((ushort4*)cp)[tid] = o;
}

// ---------- launch ----------
extern "C" void kernel_launch(void* const* d_in, const int* in_sizes, int n_in,
                              void* d_out, int out_size, void* d_ws, size_t ws_size,
                              hipStream_t stream) {
  const float* z = (const float*)d_in[0];
  const float* x = (const float*)d_in[1];
  const float* y = (const float*)d_in[2];
  const float* Wq = (const float*)d_in[3];
  const float* bq = (const float*)d_in[4];
  const float* Wk = (const float*)d_in[5];
  const float* bk = (const float*)d_in[6];
  const float* Wv = (const float*)d_in[7];
  const float* bv = (const float*)d_in[8];
  float* out = (float*)d_out;

  // ws (288 MiB):
  // P01 [0,128M):   y^T hi/lo planes -> es fp32 -> z_t bf16 [0,64M) | v_bf [64M,128M)
  // P23 [128,256M): x^T hi/lo planes -> ec fp32 (attn bf16 in-place, row stride 2048)
  // P4  [256,288M): q_t fp32 16M | k_t fp32 16M -> wv bf16 2M
  char* ws = (char*)d_ws;
  unsigned short* yth = (unsigned short*)ws;
  unsigned short* ytl = yth + 33554432;
  float* es = (float*)ws;
  unsigned short* z_t = (unsigned short*)ws;
  unsigned short* v_bf = z_t + 33554432;
  char* wsB = ws + 134217728;
  unsigned short* xth = (unsigned short*)wsB;
  unsigned short* xtl = xth + 33554432;
  float* ec = (float*)wsB;
  unsigned short* attn = (unsigned short*)wsB;
  char* wsC = ws + 268435456;
  float* q_t = (float*)wsC;            // [32][1024][128]
  float* k_t = q_t + 4194304;
  unsigned short* wv = (unsigned short*)wsC;

  dim3 blk(256);
  // transposed hi/lo planes for x and y
  hipLaunchKernelGGL(k_tsplitT, dim3(16, 16, 32), blk, 0, stream, x, xth, xtl);
  hipLaunchKernelGGL(k_tsplitT, dim3(16, 16, 32), blk, 0, stream, y, yth, ytl);
  // merged q/k projection -> q_t,k_t fp32 [n][128]
  hipLaunchKernelGGL(k_qk3p, dim3(8, 2, 32), blk, 0, stream,
                     xth, xtl, yth, ytl, Wq, Wk, bq, bk, q_t, k_t);
  // es[b][m][d] = x[m][:] . y[d][:]  (fp32 from d_in) -> P01 (y planes dead)
  hipLaunchKernelGGL((k_mfma3<0>), dim3(8, 8, 32), blk, 0, stream,
                     x, 1024, 1048576LL, y, 1024, 1048576LL, es, 1024, 1048576LL,
                     (const float*)nullptr, 1024);
  // ec[b][i][j] = q_t[i][:] . k_t[j][:]  (K=128) -> P23 (x planes dead)
  hipLaunchKernelGGL((k_mfma3<0>), dim3(8, 8, 32), blk, 0, stream,
                     q_t, 128, 131072LL, k_t, 128, 131072LL, ec, 1024, 1048576LL,
                     (const float*)nullptr, 128);
  // triple softmax -> attn bf16 in-place in ec rows
  hipLaunchKernelGGL(k_combine, dim3(32768), blk, 0, stream, ec, es);
  // z^T bf16 (es dead) ; Wv bf16 (q_t/k_t dead)
  hipLaunchKernelGGL(k_transpbf, dim3(16, 16, 32), blk, 0, stream, z, z_t);
  hipLaunchKernelGGL(k_convert, dim3(512), blk, 0, stream, Wv, wv, 1048576);
  // v[b][o][n] = Wv[o][:] . z_t[n][:] + bv[o] -> bf16
  hipLaunchKernelGGL((k_mfma256<1, true, false>), dim3(4, 4, 32), dim3(512), 0, stream,
                     wv, 1024, 0LL, z_t, 1024, 1048576LL, (void*)v_bf, 1024, 1048576LL,
                     bv, (const float*)nullptr, 0LL, 1024);
  // out[b][c][m] = z[b][c][m] + v[c][:] . attn[m][:]
  hipLaunchKernelGGL((k_mfma256<0, false, true>), dim3(4, 4, 32), dim3(512), 0, stream,
                     v_bf, 1024, 1048576LL, attn, 2048, 2097152LL, (void*)out, 1024, 1048576LL,
                     (const float*)nullptr, z, 1048576LL, 1024);
}